// Round 11
// baseline (134921.863 us; speedup 1.0000x reference)
//
#include <hip/hip_runtime.h>
#include <math.h>

#define DIM  1024
#define SEQ  64
#define HDIM 256
#define NBLK 256
#define SLOT_STRIDE 32   // 32 u32 = 128 B

typedef float f4 __attribute__((ext_vector_type(4)));

// ---------------- wave / block reduction helpers ----------------
__device__ __forceinline__ float wsum(float v){
  v += __shfl_xor(v, 32, 64); v += __shfl_xor(v, 16, 64); v += __shfl_xor(v, 8, 64);
  v += __shfl_xor(v, 4, 64);  v += __shfl_xor(v, 2, 64);  v += __shfl_xor(v, 1, 64);
  return v;
}
__device__ __forceinline__ float wmax(float v){
  v = fmaxf(v, __shfl_xor(v, 32, 64)); v = fmaxf(v, __shfl_xor(v, 16, 64));
  v = fmaxf(v, __shfl_xor(v, 8, 64));  v = fmaxf(v, __shfl_xor(v, 4, 64));
  v = fmaxf(v, __shfl_xor(v, 2, 64));  v = fmaxf(v, __shfl_xor(v, 1, 64));
  return v;
}
__device__ __forceinline__ float2 breduce2(float va, float vb, float* red){
  int tid = threadIdx.x;
  va = wsum(va); vb = wsum(vb);
  if ((tid & 63) == 0){ red[(tid >> 6) * 2] = va; red[(tid >> 6) * 2 + 1] = vb; }
  __syncthreads();
  float ra = red[0] + red[2] + red[4] + red[6];
  float rb = red[1] + red[3] + red[5] + red[7];
  __syncthreads();
  return make_float2(ra, rb);
}

// ---------------- device-coherent payload access (HIP atomics, proven R1-R8) ----
__device__ __forceinline__ float ldc(const float* p){
  return __hip_atomic_load(p, __ATOMIC_RELAXED, __HIP_MEMORY_SCOPE_AGENT);
}
__device__ __forceinline__ void stc(float* p, float v){
  __hip_atomic_store(p, v, __ATOMIC_RELAXED, __HIP_MEMORY_SCOPE_AGENT);
}

// ---- payload-carrying sync lines: 16B = [p0,p1,p2,epoch] ----
// Protocol (R10 post-mortem): STORE with sc1 (device-visible, probe-invalidates
// remote cached copies). POLL with sc0 loads (bypass per-CU L1, serve from XCD
// L2 -> cheap spins; R10 showed sc-bypass polls cost 700MB of L2-fill traffic).
// A single aligned 16B load can't mix old payload with new epoch, so a stale
// line only delays, never corrupts. Fallback to sc1 polling after 2048 spins.
__device__ __forceinline__ void st_line(float* p, float x, float y, float z, float w){
  f4 v; v.x = x; v.y = y; v.z = z; v.w = w;
  asm volatile("global_store_dwordx4 %0, %1, off sc1" :: "v"(p), "v"(v) : "memory");
}
__device__ __forceinline__ f4 ld_line_fast(const float* p){   // L2-served
  f4 r;
  asm volatile("global_load_dwordx4 %0, %1, off sc0\n\ts_waitcnt vmcnt(0)"
               : "=v"(r) : "v"(p) : "memory");
  return r;
}
__device__ __forceinline__ f4 ld_line_coh(const float* p){    // guaranteed-fresh
  f4 r;
  asm volatile("global_load_dwordx4 %0, %1, off sc1\n\ts_waitcnt vmcnt(0)"
               : "=v"(r) : "v"(p) : "memory");
  return r;
}
__device__ __forceinline__ f4 poll1_slow(const float* p, float tgt){
  unsigned s = 0;
  for (;;){
    f4 r = ld_line_coh(p);
    if (r.w >= tgt) return r;
    if (++s > 100000000u) return r;   // safety valve
  }
}
// poll 4 lines concurrently (fast sc0 path; sc1 fallback after 2048 spins)
__device__ __forceinline__ void poll4(const float* base, int tid, float tgt,
                                      f4& r0, f4& r1, f4& r2, f4& r3){
  const float* p0 = base + (size_t)tid * 32;
  const float* p1 = base + (size_t)(tid + 256) * 32;
  const float* p2 = base + (size_t)(tid + 512) * 32;
  const float* p3 = base + (size_t)(tid + 768) * 32;
  unsigned spins = 0;
  for (;;){
    asm volatile(
      "global_load_dwordx4 %0, %4, off sc0\n\t"
      "global_load_dwordx4 %1, %5, off sc0\n\t"
      "global_load_dwordx4 %2, %6, off sc0\n\t"
      "global_load_dwordx4 %3, %7, off sc0\n\t"
      "s_waitcnt vmcnt(0)"
      : "=&v"(r0), "=&v"(r1), "=&v"(r2), "=&v"(r3)
      : "v"(p0), "v"(p1), "v"(p2), "v"(p3)
      : "memory");
    if (r0.w >= tgt && r1.w >= tgt && r2.w >= tgt && r3.w >= tgt) return;
    if (++spins > 2048u){
      r0 = poll1_slow(p0, tgt); r1 = poll1_slow(p1, tgt);
      r2 = poll1_slow(p2, tgt); r3 = poll1_slow(p3, tgt);
      return;
    }
  }
}
__device__ __forceinline__ f4 poll1(const float* p, float tgt){
  unsigned spins = 0;
  for (;;){
    f4 r = ld_line_fast(p);
    if (r.w >= tgt) return r;
    if (++spins > 2048u) return poll1_slow(p, tgt);
  }
}

__device__ __forceinline__ void spin_ge(unsigned* p, unsigned ep){
  unsigned spins = 0;
  while (__hip_atomic_load(p, __ATOMIC_RELAXED, __HIP_MEMORY_SCOPE_AGENT) < ep){
    if (++spins > 4194304u){
      unsigned s2 = 0;
      while (__hip_atomic_load(p, __ATOMIC_ACQUIRE, __HIP_MEMORY_SCOPE_AGENT) < ep){
        __builtin_amdgcn_s_sleep(2);
        if (++s2 > 100000000u) break;
      }
      return;
    }
  }
}
// classic barrier, used only for the 3 P-stages
__device__ __forceinline__ void gsync(unsigned* slots, unsigned ep, int bid, int tid){
  asm volatile("s_waitcnt vmcnt(0)" ::: "memory");
  __syncthreads();
  if (tid == 0)
    __hip_atomic_store(&slots[bid * SLOT_STRIDE], ep, __ATOMIC_RELAXED, __HIP_MEMORY_SCOPE_AGENT);
  spin_ge(&slots[tid * SLOT_STRIDE], ep);
  __syncthreads();
  asm volatile("" ::: "memory");
}

// ---------------- Cm = vm_w @ vr_w (only remaining prologue kernel) ----------------
__global__ void matmul_nn_1024(const float* __restrict__ A, const float* __restrict__ B,
                               float* __restrict__ Cc){
  __shared__ float As[32][33];
  __shared__ float Bs[32][33];
  int tb = blockIdx.x * 32, ta = blockIdx.y * 32;
  int tx = threadIdx.x & 31, ty = threadIdx.x >> 5;
  float acc[4] = {0.f, 0.f, 0.f, 0.f};
  for (int k0 = 0; k0 < 1024; k0 += 32){
    for (int r = ty; r < 32; r += 8) As[r][tx] = A[(size_t)(ta + r) * 1024 + k0 + tx];
    for (int r = ty; r < 32; r += 8) Bs[r][tx] = B[(size_t)(k0 + r) * 1024 + tb + tx];
    __syncthreads();
    #pragma unroll
    for (int kk = 0; kk < 32; ++kk){
      float bv = Bs[kk][tx];
      #pragma unroll
      for (int m = 0; m < 4; ++m) acc[m] = fmaf(As[ty + 8 * m][kk], bv, acc[m]);
    }
    __syncthreads();
  }
  for (int m = 0; m < 4; ++m) Cc[(size_t)(ta + ty + 8 * m) * 1024 + tb + tx] = acc[m];
}

// ---------------- the persistent autoregressive decode ----------------
struct CoopArgs {
  const float *hs, *hid_w, *hid_b;
  const float *sa_in_w, *sa_in_b, *sa_out_w, *sa_out_b;
  const float *ca_in_w, *ca_in_b, *ca_out_w, *ca_out_b;
  const float *ln1_g, *ln1_b, *ln2_g, *ln2_b, *ln3_g, *ln3_b;
  const float *ff1_w, *ff1_b, *ff2_w, *ff2_b;
  const float *vr_w, *vr_b, *vm_w, *vm_b, *obj_w;
  const float *Cm;
  float *mem, *vtmp, *cac, *kc;
  float *lS1, *lU, *lH, *lW, *lE, *lSC;   // payload line regions (128B lines)
  float *out;
  unsigned *bar;
};

__global__ void __launch_bounds__(256, 2) decode_loop(CoopArgs a){
  const int tid = threadIdx.x, bid = blockIdx.x;
  const int wave = tid >> 6, lane = tid & 63;
  const int gw = bid * 4 + wave;            // global wave id / row, 0..1023
  __shared__ float smA[2048];
  __shared__ float smB[1024];
  __shared__ float smC[1024];
  __shared__ float scp[256];
  __shared__ float red[8];
  unsigned ep = 0;

  // pe-on-the-fly constants for this thread's 4 dims
  const float NLOG = -9.210340371976184f / 1024.0f;   // -ln(10000)/D
  float div4[4]; int par4[4];
  #pragma unroll
  for (int k = 0; k < 4; ++k){
    int d = tid + 256 * k;
    div4[k] = __expf((float)(2 * (d >> 1)) * NLOG);
    par4[k] = d & 1;
  }

  // ======== P-stages (classic barrier; each wave covers ALL 64 t) ========
  // P1: mem[t][gw] = hid_w[gw].hs[t] + hid_b[gw]
  {
    float pw[16];
    const float* pr = a.hid_w + (size_t)gw * DIM;
    #pragma unroll
    for (int k = 0; k < 16; ++k) pw[k] = pr[lane + 64 * k];
    float bias = a.hid_b[gw];
    for (int t = 0; t < 64; ++t){
      const float* xr = a.hs + (size_t)t * DIM;
      float acc = 0.f;
      #pragma unroll
      for (int k = 0; k < 16; ++k) acc = fmaf(pw[k], xr[lane + 64 * k], acc);
      acc = wsum(acc);
      if (lane == 0) stc(a.mem + (size_t)t * DIM + gw, acc + bias);
    }
  }
  ++ep; gsync(a.bar, ep, bid, tid);

  // P2: vtmp[t][gw] = ca_wv[gw].mem[t] + ca_bv[gw]
  {
    float pw[16];
    const float* pr = a.ca_in_w + (size_t)(2 * DIM + gw) * DIM;
    #pragma unroll
    for (int k = 0; k < 16; ++k) pw[k] = pr[lane + 64 * k];
    float bias = a.ca_in_b[2 * DIM + gw];
    for (int t = 0; t < 64; ++t){
      const float* xr = a.mem + (size_t)t * DIM;
      #pragma unroll
      for (int k = 0; k < 4; ++k) smA[tid + 256 * k] = ldc(xr + tid + 256 * k);
      __syncthreads();
      float acc = 0.f;
      #pragma unroll
      for (int k = 0; k < 16; ++k) acc = fmaf(pw[k], smA[lane + 64 * k], acc);
      acc = wsum(acc);
      if (lane == 0) stc(a.vtmp + (size_t)t * DIM + gw, acc + bias);
      __syncthreads();
    }
  }
  ++ep; gsync(a.bar, ep, bid, tid);

  // P3: cac[t][gw] = ca_out_w[gw].vtmp[t] + ca_out_b[gw]
  {
    float pw[16];
    const float* pr = a.ca_out_w + (size_t)gw * DIM;
    #pragma unroll
    for (int k = 0; k < 16; ++k) pw[k] = pr[lane + 64 * k];
    float bias = a.ca_out_b[gw];
    for (int t = 0; t < 64; ++t){
      const float* xr = a.vtmp + (size_t)t * DIM;
      #pragma unroll
      for (int k = 0; k < 4; ++k) smA[tid + 256 * k] = ldc(xr + tid + 256 * k);
      __syncthreads();
      float acc = 0.f;
      #pragma unroll
      for (int k = 0; k < 16; ++k) acc = fmaf(pw[k], smA[lane + 64 * k], acc);
      acc = wsum(acc);
      if (lane == 0) stc(a.cac + (size_t)t * DIM + gw, acc + bias);
      __syncthreads();
    }
  }
  ++ep; gsync(a.bar, ep, bid, tid);

  // ---- main weight rows into registers (128 floats/thread)
  float wq[16], wk[16], wv[16], wo[16], f1a[16], f1b[16], f2[32];
  {
    const float* pq = a.sa_in_w + (size_t)gw * DIM;
    const float* pk = a.sa_in_w + (size_t)(DIM + gw) * DIM;
    const float* pv = a.sa_in_w + (size_t)(2 * DIM + gw) * DIM;
    const float* po = a.sa_out_w + (size_t)gw * DIM;
    const float* p1a = a.ff1_w + (size_t)(2 * gw) * DIM;
    const float* p1b = a.ff1_w + (size_t)(2 * gw + 1) * DIM;
    const float* p2 = a.ff2_w + (size_t)gw * 2048;
    #pragma unroll
    for (int k = 0; k < 16; ++k){
      int d = lane + 64 * k;
      wq[k] = pq[d]; wk[k] = pk[d]; wv[k] = pv[d]; wo[k] = po[d];
      f1a[k] = p1a[d]; f1b[k] = p1b[d];
    }
    #pragma unroll
    for (int k = 0; k < 32; ++k) f2[k] = p2[lane + 64 * k];
  }
  const float b_q  = a.sa_in_b[gw];
  const float b_k  = a.sa_in_b[DIM + gw];
  const float b_v  = a.sa_in_b[2 * DIM + gw];
  const float b_o  = a.sa_out_b[gw];
  const float b_1a = a.ff1_b[2 * gw];
  const float b_1b = a.ff1_b[2 * gw + 1];
  const float b_2  = a.ff2_b[gw];
  const float b_vr = a.vr_b[gw];
  float cbv;
  {
    const float* pv = a.vm_w + (size_t)gw * DIM;
    float acc = 0.f;
    #pragma unroll
    for (int k = 0; k < 16; ++k) acc = fmaf(pv[lane + 64 * k], a.vr_b[lane + 64 * k], acc);
    cbv = wsum(acc) + a.vm_b[gw] + a.obj_w[(size_t)gw * 80];
  }

  // running projected-V cache: lane j holds c^h_j = wo_gw[head h] . V_j[head h]
  float c0 = 0.f, c1 = 0.f, c2 = 0.f, c3 = 0.f;

  const bool is_score = (bid < 16);
  const int sc_h  = bid >> 2;
  const int sc_jg = bid & 3;
  const int swid  = bid * 4 + wave;                    // 0..63 for score blocks
  const float sc_slope = 1.0f / (float)(4 << (2 * sc_h));

  for (int i = 0; i < SEQ; ++i){
    const float posf = (float)(i % 30);
    const float epf  = (float)(i + 1);
    float remb;

    // ---- S1: stage x = emb[i]+pe[i]; QKV; publish (q,k,v) line; kc row i
    {
      if (i == 0){
        #pragma unroll
        for (int k = 0; k < 4; ++k){
          int d = tid + 256 * k;
          float arg = posf * div4[k];
          float pe = par4[k] ? __cosf(arg) : __sinf(arg);
          smA[d] = a.obj_w[(size_t)d * 80] + pe;
        }
      } else {
        f4 r0, r1, r2, r3;
        poll4(a.lE, tid, (float)i, r0, r1, r2, r3);
        float ev[4] = {r0.x, r1.x, r2.x, r3.x};
        #pragma unroll
        for (int k = 0; k < 4; ++k){
          int d = tid + 256 * k;
          float arg = posf * div4[k];
          float pe = par4[k] ? __cosf(arg) : __sinf(arg);
          smA[d] = ev[k] + pe;
        }
      }
      __syncthreads();
      remb = smA[gw];                      // residual (= emb+pe at dim gw)
      float aq = 0.f, ak = 0.f, av = 0.f;
      #pragma unroll
      for (int k = 0; k < 16; ++k){
        float x = smA[lane + 64 * k];
        aq = fmaf(wq[k], x, aq);
        ak = fmaf(wk[k], x, ak);
        av = fmaf(wv[k], x, av);
      }
      aq = wsum(aq); ak = wsum(ak); av = wsum(av);
      if (lane == 0){
        stc(a.kc + (size_t)i * DIM + gw, ak + b_k);     // K cache for future iters
        asm volatile("s_waitcnt vmcnt(0)" ::: "memory"); // drain before line store
        st_line(a.lS1 + (size_t)gw * 32, aq + b_q, ak + b_k, av + b_v, epf);
      }
    }

    // ---- S2: poll qkv lines; c-update; scores (16 blocks); softmax; u line
    {
      f4 r0, r1, r2, r3;
      poll4(a.lS1, tid, epf, r0, r1, r2, r3);
      smB[tid] = r0.z; smB[tid + 256] = r1.z; smB[tid + 512] = r2.z; smB[tid + 768] = r3.z; // V row
      smC[tid] = r0.x; smC[tid + 256] = r1.x; smC[tid + 512] = r2.x; smC[tid + 768] = r3.x; // q row
      __syncthreads();
      // c-update from V row
      float p0 = 0.f, p1 = 0.f, p2 = 0.f, p3 = 0.f;
      #pragma unroll
      for (int k = 0; k < 4; ++k){
        p0 = fmaf(wo[k],      smB[lane + 64 * k],        p0);
        p1 = fmaf(wo[k + 4],  smB[lane + 64 * (k + 4)],  p1);
        p2 = fmaf(wo[k + 8],  smB[lane + 64 * (k + 8)],  p2);
        p3 = fmaf(wo[k + 12], smB[lane + 64 * (k + 12)], p3);
      }
      p0 = wsum(p0); p1 = wsum(p1); p2 = wsum(p2); p3 = wsum(p3);
      if (lane == i){ c0 = p0; c1 = p1; c2 = p2; c3 = p3; }
      // scores (block-uniform branch)
      if (is_score){
        float sj[4];
        #pragma unroll
        for (int jj = 0; jj < 4; ++jj){
          int j = sc_jg * 16 + wave * 4 + jj;
          if (j <= i){
            const float* kr = a.kc + (size_t)j * DIM + sc_h * HDIM;
            float acc = 0.f;
            #pragma unroll
            for (int m = 0; m < 4; ++m)
              acc = fmaf(smC[sc_h * HDIM + m * 64 + lane], ldc(kr + m * 64 + lane), acc);
            acc = wsum(acc);
            sj[jj] = acc * 0.0625f - sc_slope * (float)((i - j) / 30);
          } else sj[jj] = 0.f;
        }
        if (lane == 0){
          st_line(a.lSC + (size_t)(swid * 2) * 32,     sj[0], sj[1], 0.f, epf);
          st_line(a.lSC + (size_t)(swid * 2 + 1) * 32, sj[2], sj[3], 0.f, epf);
        }
      }
      if (tid < 128){
        f4 r = poll1(a.lSC + (size_t)tid * 32, epf);
        int sw = tid >> 1, half = tid & 1;
        int sb = sw >> 2, wv2 = sw & 3;
        int h = sb >> 2, jg = sb & 3;
        int j0 = jg * 16 + wv2 * 4 + half * 2;
        scp[h * 64 + j0] = r.x; scp[h * 64 + j0 + 1] = r.y;
      }
      __syncthreads();
      // softmax (wave = head; wave owns its scp row)
      {
        const int h = wave;
        float sv = (lane <= i) ? scp[h * 64 + lane] : -3.0e38f;
        float mx = wmax(sv);
        float p = (lane <= i) ? __expf(sv - mx) : 0.f;
        float sum = wsum(p);
        scp[h * 64 + lane] = p / sum;
      }
      __syncthreads();
      float t = scp[lane] * c0 + scp[64 + lane] * c1 + scp[128 + lane] * c2 + scp[192 + lane] * c3;
      t = wsum(t);
      if (lane == 0) st_line(a.lU + (size_t)gw * 32, remb + t + b_o, 0.f, 0.f, epf);
    }

    // ---- S3: poll u; ln1 -> +cac -> ln2; ff1 -> hb line
    float x2v;
    {
      float cr[4];
      #pragma unroll
      for (int k = 0; k < 4; ++k) cr[k] = ldc(a.cac + (size_t)i * DIM + tid + 256 * k);
      f4 r0, r1, r2, r3;
      poll4(a.lU, tid, epf, r0, r1, r2, r3);
      smA[tid] = r0.x; smA[tid + 256] = r1.x; smA[tid + 512] = r2.x; smA[tid + 768] = r3.x;
      __syncthreads();
      float sa = 0.f, sb = 0.f;
      #pragma unroll
      for (int k = 0; k < 4; ++k){ float x = smA[tid + 256 * k]; sa += x; sb = fmaf(x, x, sb); }
      float2 r = breduce2(sa, sb, red);
      float mean = r.x * (1.f / 1024.f);
      float var  = r.y * (1.f / 1024.f) - mean * mean;
      float rs = 1.f / sqrtf(var + 1e-5f);
      float tv[4];
      float ta = 0.f, tb = 0.f;
      #pragma unroll
      for (int k = 0; k < 4; ++k){
        int d = tid + 256 * k;
        float x1 = (smA[d] - mean) * rs * a.ln1_g[d] + a.ln1_b[d];
        tv[k] = x1 + cr[k];
        ta += tv[k]; tb = fmaf(tv[k], tv[k], tb);
      }
      float2 r2v = breduce2(ta, tb, red);
      float mean2 = r2v.x * (1.f / 1024.f);
      float var2  = r2v.y * (1.f / 1024.f) - mean2 * mean2;
      float rs2 = 1.f / sqrtf(var2 + 1e-5f);
      #pragma unroll
      for (int k = 0; k < 4; ++k){
        int d = tid + 256 * k;
        smA[d] = (tv[k] - mean2) * rs2 * a.ln2_g[d] + a.ln2_b[d];
      }
      __syncthreads();
      x2v = smA[gw];
      float acc0 = 0.f, acc1 = 0.f;
      #pragma unroll
      for (int k = 0; k < 16; ++k){
        float x = smA[lane + 64 * k];
        acc0 = fmaf(f1a[k], x, acc0);
        acc1 = fmaf(f1b[k], x, acc1);
      }
      acc0 = wsum(acc0); acc1 = wsum(acc1);
      if (lane == 0)
        st_line(a.lH + (size_t)gw * 32, fmaxf(acc0 + b_1a, 0.f), fmaxf(acc1 + b_1b, 0.f), 0.f, epf);
    }

    // ---- S4: poll hb; ff2 -> w line ; prefetch vr_w/Cm rows
    float vrr[16], cmr[16];
    {
      const float* pr = a.vr_w + (size_t)gw * DIM;
      const float* pc = a.Cm + (size_t)gw * DIM;
      #pragma unroll
      for (int k = 0; k < 16; ++k){ vrr[k] = pr[lane + 64 * k]; cmr[k] = pc[lane + 64 * k]; }
      f4 r0, r1, r2, r3;
      poll4(a.lH, tid, epf, r0, r1, r2, r3);
      smA[2 * tid] = r0.x;           smA[2 * tid + 1] = r0.y;
      smA[2 * (tid + 256)] = r1.x;   smA[2 * (tid + 256) + 1] = r1.y;
      smA[2 * (tid + 512)] = r2.x;   smA[2 * (tid + 512) + 1] = r2.y;
      smA[2 * (tid + 768)] = r3.x;   smA[2 * (tid + 768) + 1] = r3.y;
      __syncthreads();
      float acc = 0.f;
      #pragma unroll
      for (int k = 0; k < 32; ++k) acc = fmaf(f2[k], smA[lane + 64 * k], acc);
      acc = wsum(acc);
      if (lane == 0) st_line(a.lW + (size_t)gw * 32, x2v + acc + b_2, 0.f, 0.f, epf);
    }

    // ---- S5: poll w; ln3; out row i; recurrence -> emb line
    {
      f4 r0, r1, r2, r3;
      poll4(a.lW, tid, epf, r0, r1, r2, r3);
      smA[tid] = r0.x; smA[tid + 256] = r1.x; smA[tid + 512] = r2.x; smA[tid + 768] = r3.x;
      __syncthreads();
      float sa = 0.f, sb = 0.f;
      #pragma unroll
      for (int k = 0; k < 4; ++k){ float x = smA[tid + 256 * k]; sa += x; sb = fmaf(x, x, sb); }
      float2 r = breduce2(sa, sb, red);
      float mean = r.x * (1.f / 1024.f);
      float var  = r.y * (1.f / 1024.f) - mean * mean;
      float rs = 1.f / sqrtf(var + 1e-5f);
      float ov[4];
      #pragma unroll
      for (int k = 0; k < 4; ++k){
        int d = tid + 256 * k;
        ov[k] = (smA[d] - mean) * rs * a.ln3_g[d] + a.ln3_b[d];
      }
      __syncthreads();
      #pragma unroll
      for (int k = 0; k < 4; ++k) smA[tid + 256 * k] = ov[k];
      __syncthreads();
      float ar = 0.f, ac = 0.f;
      #pragma unroll
      for (int k = 0; k < 16; ++k){
        float x = smA[lane + 64 * k];
        ar = fmaf(vrr[k], x, ar);
        ac = fmaf(cmr[k], x, ac);
      }
      ar = wsum(ar); ac = wsum(ac);
      if (lane == 0){
        a.out[(size_t)i * DIM + gw] = ar + b_vr;
        st_line(a.lE + (size_t)gw * 32, ac + cbv, 0.f, 0.f, epf);
      }
    }
  }
}

// ---------------- host launcher ----------------
extern "C" void kernel_launch(void* const* d_in, const int* in_sizes, int n_in,
                              void* d_out, int out_size, void* d_ws, size_t ws_size,
                              hipStream_t stream){
  const float* hs       = (const float*)d_in[0];
  const float* hid_w    = (const float*)d_in[1];
  const float* hid_b    = (const float*)d_in[2];
  const float* obj_w    = (const float*)d_in[3];
  const float* sa_in_w  = (const float*)d_in[4];
  const float* sa_in_b  = (const float*)d_in[5];
  const float* sa_out_w = (const float*)d_in[6];
  const float* sa_out_b = (const float*)d_in[7];
  const float* ca_in_w  = (const float*)d_in[8];
  const float* ca_in_b  = (const float*)d_in[9];
  const float* ca_out_w = (const float*)d_in[10];
  const float* ca_out_b = (const float*)d_in[11];
  const float* ln1_g    = (const float*)d_in[12];
  const float* ln1_b    = (const float*)d_in[13];
  const float* ln2_g    = (const float*)d_in[14];
  const float* ln2_b    = (const float*)d_in[15];
  const float* ln3_g    = (const float*)d_in[16];
  const float* ln3_b    = (const float*)d_in[17];
  const float* ff1_w    = (const float*)d_in[18];
  const float* ff1_b    = (const float*)d_in[19];
  const float* ff2_w    = (const float*)d_in[20];
  const float* ff2_b    = (const float*)d_in[21];
  const float* vr_w     = (const float*)d_in[22];
  const float* vr_b     = (const float*)d_in[23];
  const float* vm_w     = (const float*)d_in[24];
  const float* vm_b     = (const float*)d_in[25];

  float* ws = (float*)d_ws;
  float* mem  = ws;                 // 65536
  float* vtmp = ws + 65536;         // 65536
  float* cac  = ws + 131072;        // 65536
  float* kc   = ws + 196608;        // 65536
  float* Cm   = ws + 262144;        // 1048576
  float* lS1  = ws + 1310720;       // 1024 lines * 32 floats = 32768
  float* lU   = ws + 1343488;       // 32768
  float* lH   = ws + 1376256;       // 32768
  float* lW   = ws + 1409024;       // 32768
  float* lE   = ws + 1441792;       // 32768
  float* lSC  = ws + 1474560;       // 128 lines * 32 = 4096
  unsigned* bar = (unsigned*)(ws + 1478656);   // 256*32 u32 = 8192 u32

  // zero all line regions + P-stage barrier slots (re-poison safe)
  hipMemsetAsync((void*)lS1, 0, (size_t)(167936 + 8192) * 4, stream);

  // Cm = vm_w @ vr_w  (folds the two recurrence gemvs)
  matmul_nn_1024<<<dim3(32, 32), 256, 0, stream>>>(vm_w, vr_w, Cm);

  CoopArgs A;
  A.hs = hs; A.hid_w = hid_w; A.hid_b = hid_b;
  A.sa_in_w = sa_in_w; A.sa_in_b = sa_in_b; A.sa_out_w = sa_out_w; A.sa_out_b = sa_out_b;
  A.ca_in_w = ca_in_w; A.ca_in_b = ca_in_b; A.ca_out_w = ca_out_w; A.ca_out_b = ca_out_b;
  A.ln1_g = ln1_g; A.ln1_b = ln1_b; A.ln2_g = ln2_g; A.ln2_b = ln2_b; A.ln3_g = ln3_g; A.ln3_b = ln3_b;
  A.ff1_w = ff1_w; A.ff1_b = ff1_b; A.ff2_w = ff2_w; A.ff2_b = ff2_b;
  A.vr_w = vr_w; A.vr_b = vr_b; A.vm_w = vm_w; A.vm_b = vm_b; A.obj_w = obj_w;
  A.Cm = Cm;
  A.mem = mem; A.vtmp = vtmp; A.cac = cac; A.kc = kc;
  A.lS1 = lS1; A.lU = lU; A.lH = lH; A.lW = lW; A.lE = lE; A.lSC = lSC;
  A.out = (float*)d_out;
  A.bar = bar;

  void* params[1] = { &A };
  hipError_t e = hipLaunchCooperativeKernel((void*)decode_loop, dim3(NBLK), dim3(256), params, 0, stream);
  if (e != hipSuccess){
    decode_loop<<<dim3(NBLK), dim3(256), 0, stream>>>(A);
  }
}

// Round 12
// 3615.454 us; speedup vs baseline: 37.3181x; 37.3181x over previous
//
#include <hip/hip_runtime.h>
#include <math.h>

#define DIM  1024
#define SEQ  64
#define HDIM 256
#define NBLK 256
#define SLOT_STRIDE 32   // 32 u32 = 128 B
#define LQ 16            // u64 per 128B line

typedef unsigned long long u64;

// ---------------- wave / block reduction helpers ----------------
__device__ __forceinline__ float wsum(float v){
  v += __shfl_xor(v, 32, 64); v += __shfl_xor(v, 16, 64); v += __shfl_xor(v, 8, 64);
  v += __shfl_xor(v, 4, 64);  v += __shfl_xor(v, 2, 64);  v += __shfl_xor(v, 1, 64);
  return v;
}
__device__ __forceinline__ float wmax(float v){
  v = fmaxf(v, __shfl_xor(v, 32, 64)); v = fmaxf(v, __shfl_xor(v, 16, 64));
  v = fmaxf(v, __shfl_xor(v, 8, 64));  v = fmaxf(v, __shfl_xor(v, 4, 64));
  v = fmaxf(v, __shfl_xor(v, 2, 64));  v = fmaxf(v, __shfl_xor(v, 1, 64));
  return v;
}
__device__ __forceinline__ float2 breduce2(float va, float vb, float* red){
  int tid = threadIdx.x;
  va = wsum(va); vb = wsum(vb);
  if ((tid & 63) == 0){ red[(tid >> 6) * 2] = va; red[(tid >> 6) * 2 + 1] = vb; }
  __syncthreads();
  float ra = red[0] + red[2] + red[4] + red[6];
  float rb = red[1] + red[3] + red[5] + red[7];
  __syncthreads();
  return make_float2(ra, rb);
}

// ---------------- proven device-coherent primitives (R1-R8) ----------------
__device__ __forceinline__ float ldc(const float* p){
  return __hip_atomic_load(p, __ATOMIC_RELAXED, __HIP_MEMORY_SCOPE_AGENT);
}
__device__ __forceinline__ void stc(float* p, float v){
  __hip_atomic_store(p, v, __ATOMIC_RELAXED, __HIP_MEMORY_SCOPE_AGENT);
}
// 64-bit payload+epoch slot: low32 = float bits, high32 = epoch (uint).
// 8B naturally-aligned atomic cannot tear; epoch+payload arrive in ONE
// proven-coherent load -> 1-RTT handoff with R8's coherence behavior.
__device__ __forceinline__ void stq(u64* p, float v, unsigned ep){
  u64 u = ((u64)ep << 32) | (u64)__float_as_uint(v);
  __hip_atomic_store(p, u, __ATOMIC_RELAXED, __HIP_MEMORY_SCOPE_AGENT);
}
__device__ __forceinline__ u64 ldq(const u64* p){
  return __hip_atomic_load(p, __ATOMIC_RELAXED, __HIP_MEMORY_SCOPE_AGENT);
}
__device__ __forceinline__ float qval(u64 u){ return __uint_as_float((unsigned)u); }
__device__ __forceinline__ unsigned qep(u64 u){ return (unsigned)(u >> 32); }

// poll 4 lines x 1 slot (lU, lW, lE)
__device__ __forceinline__ void poll41(const u64* base, int tid, unsigned ep, float* v){
  const u64 *l0 = base + (size_t)tid * LQ,        *l1 = base + (size_t)(tid + 256) * LQ;
  const u64 *l2 = base + (size_t)(tid + 512) * LQ, *l3 = base + (size_t)(tid + 768) * LQ;
  unsigned spins = 0;
  for (;;){
    u64 a = ldq(l0), b = ldq(l1), c = ldq(l2), d = ldq(l3);
    if (qep(a) >= ep && qep(b) >= ep && qep(c) >= ep && qep(d) >= ep){
      v[0] = qval(a); v[1] = qval(b); v[2] = qval(c); v[3] = qval(d);
      return;
    }
    if (++spins > 100000000u){ v[0]=qval(a); v[1]=qval(b); v[2]=qval(c); v[3]=qval(d); return; }
  }
}
// poll 4 lines x 2 slots (lS1: q,v ; lH: h0,h1)
__device__ __forceinline__ void poll42(const u64* base, int tid, unsigned ep,
                                       float* v0, float* v1){
  const u64 *l0 = base + (size_t)tid * LQ,        *l1 = base + (size_t)(tid + 256) * LQ;
  const u64 *l2 = base + (size_t)(tid + 512) * LQ, *l3 = base + (size_t)(tid + 768) * LQ;
  unsigned spins = 0;
  for (;;){
    u64 a0 = ldq(l0), a1 = ldq(l0 + 1);
    u64 b0 = ldq(l1), b1 = ldq(l1 + 1);
    u64 c0 = ldq(l2), c1 = ldq(l2 + 1);
    u64 d0 = ldq(l3), d1 = ldq(l3 + 1);
    if (qep(a0) >= ep && qep(a1) >= ep && qep(b0) >= ep && qep(b1) >= ep &&
        qep(c0) >= ep && qep(c1) >= ep && qep(d0) >= ep && qep(d1) >= ep){
      v0[0] = qval(a0); v1[0] = qval(a1);
      v0[1] = qval(b0); v1[1] = qval(b1);
      v0[2] = qval(c0); v1[2] = qval(c1);
      v0[3] = qval(d0); v1[3] = qval(d1);
      return;
    }
    if (++spins > 100000000u){
      v0[0]=qval(a0); v1[0]=qval(a1); v0[1]=qval(b0); v1[1]=qval(b1);
      v0[2]=qval(c0); v1[2]=qval(c1); v0[3]=qval(d0); v1[3]=qval(d1);
      return;
    }
  }
}
// poll 1 line x 4 slots (lSC)
__device__ __forceinline__ void poll14(const u64* line, unsigned ep, float* v){
  unsigned spins = 0;
  for (;;){
    u64 a = ldq(line), b = ldq(line + 1), c = ldq(line + 2), d = ldq(line + 3);
    if (qep(a) >= ep && qep(b) >= ep && qep(c) >= ep && qep(d) >= ep){
      v[0] = qval(a); v[1] = qval(b); v[2] = qval(c); v[3] = qval(d);
      return;
    }
    if (++spins > 100000000u){ v[0]=qval(a); v[1]=qval(b); v[2]=qval(c); v[3]=qval(d); return; }
  }
}

__device__ __forceinline__ void spin_ge(unsigned* p, unsigned ep){
  unsigned spins = 0;
  while (__hip_atomic_load(p, __ATOMIC_RELAXED, __HIP_MEMORY_SCOPE_AGENT) < ep){
    if (++spins > 100000000u) break;
  }
}
// classic barrier (proven R8), used only for the 3 P-stages
__device__ __forceinline__ void gsync(unsigned* slots, unsigned ep, int bid, int tid){
  asm volatile("s_waitcnt vmcnt(0)" ::: "memory");
  __syncthreads();
  if (tid == 0)
    __hip_atomic_store(&slots[bid * SLOT_STRIDE], ep, __ATOMIC_RELAXED, __HIP_MEMORY_SCOPE_AGENT);
  spin_ge(&slots[tid * SLOT_STRIDE], ep);
  __syncthreads();
  asm volatile("" ::: "memory");
}

// ---------------- Cm = vm_w @ vr_w (only remaining prologue kernel) ----------------
__global__ void matmul_nn_1024(const float* __restrict__ A, const float* __restrict__ B,
                               float* __restrict__ Cc){
  __shared__ float As[32][33];
  __shared__ float Bs[32][33];
  int tb = blockIdx.x * 32, ta = blockIdx.y * 32;
  int tx = threadIdx.x & 31, ty = threadIdx.x >> 5;
  float acc[4] = {0.f, 0.f, 0.f, 0.f};
  for (int k0 = 0; k0 < 1024; k0 += 32){
    for (int r = ty; r < 32; r += 8) As[r][tx] = A[(size_t)(ta + r) * 1024 + k0 + tx];
    for (int r = ty; r < 32; r += 8) Bs[r][tx] = B[(size_t)(k0 + r) * 1024 + tb + tx];
    __syncthreads();
    #pragma unroll
    for (int kk = 0; kk < 32; ++kk){
      float bv = Bs[kk][tx];
      #pragma unroll
      for (int m = 0; m < 4; ++m) acc[m] = fmaf(As[ty + 8 * m][kk], bv, acc[m]);
    }
    __syncthreads();
  }
  for (int m = 0; m < 4; ++m) Cc[(size_t)(ta + ty + 8 * m) * 1024 + tb + tx] = acc[m];
}

// ---------------- the persistent autoregressive decode ----------------
struct CoopArgs {
  const float *hs, *hid_w, *hid_b;
  const float *sa_in_w, *sa_in_b, *sa_out_w, *sa_out_b;
  const float *ca_in_w, *ca_in_b, *ca_out_w, *ca_out_b;
  const float *ln1_g, *ln1_b, *ln2_g, *ln2_b, *ln3_g, *ln3_b;
  const float *ff1_w, *ff1_b, *ff2_w, *ff2_b;
  const float *vr_w, *vr_b, *vm_w, *vm_b, *obj_w;
  const float *Cm;
  float *mem, *vtmp, *cac, *kc;
  u64 *lS1, *lU, *lH, *lW, *lE, *lSC;   // payload+epoch line regions (128B lines)
  float *out;
  unsigned *bar;
};

__global__ void __launch_bounds__(256, 2) decode_loop(CoopArgs a){
  const int tid = threadIdx.x, bid = blockIdx.x;
  const int wave = tid >> 6, lane = tid & 63;
  const int gw = bid * 4 + wave;            // global wave id / row, 0..1023
  __shared__ float smA[2048];
  __shared__ float smB[1024];
  __shared__ float smC[1024];
  __shared__ float scp[256];
  __shared__ float red[8];
  unsigned bep = 0;

  // pe-on-the-fly constants for this thread's 4 dims
  const float NLOG = -9.210340371976184f / 1024.0f;   // -ln(10000)/D
  float div4[4]; int par4[4];
  #pragma unroll
  for (int k = 0; k < 4; ++k){
    int d = tid + 256 * k;
    div4[k] = __expf((float)(2 * (d >> 1)) * NLOG);
    par4[k] = d & 1;
  }

  // ======== P-stages (classic barrier; each wave covers ALL 64 t) ========
  // P1: mem[t][gw] = hid_w[gw].hs[t] + hid_b[gw]
  {
    float pw[16];
    const float* pr = a.hid_w + (size_t)gw * DIM;
    #pragma unroll
    for (int k = 0; k < 16; ++k) pw[k] = pr[lane + 64 * k];
    float bias = a.hid_b[gw];
    for (int t = 0; t < 64; ++t){
      const float* xr = a.hs + (size_t)t * DIM;
      float acc = 0.f;
      #pragma unroll
      for (int k = 0; k < 16; ++k) acc = fmaf(pw[k], xr[lane + 64 * k], acc);
      acc = wsum(acc);
      if (lane == 0) stc(a.mem + (size_t)t * DIM + gw, acc + bias);
    }
  }
  ++bep; gsync(a.bar, bep, bid, tid);

  // P2: vtmp[t][gw] = ca_wv[gw].mem[t] + ca_bv[gw]
  {
    float pw[16];
    const float* pr = a.ca_in_w + (size_t)(2 * DIM + gw) * DIM;
    #pragma unroll
    for (int k = 0; k < 16; ++k) pw[k] = pr[lane + 64 * k];
    float bias = a.ca_in_b[2 * DIM + gw];
    for (int t = 0; t < 64; ++t){
      const float* xr = a.mem + (size_t)t * DIM;
      #pragma unroll
      for (int k = 0; k < 4; ++k) smA[tid + 256 * k] = ldc(xr + tid + 256 * k);
      __syncthreads();
      float acc = 0.f;
      #pragma unroll
      for (int k = 0; k < 16; ++k) acc = fmaf(pw[k], smA[lane + 64 * k], acc);
      acc = wsum(acc);
      if (lane == 0) stc(a.vtmp + (size_t)t * DIM + gw, acc + bias);
      __syncthreads();
    }
  }
  ++bep; gsync(a.bar, bep, bid, tid);

  // P3: cac[t][gw] = ca_out_w[gw].vtmp[t] + ca_out_b[gw]
  {
    float pw[16];
    const float* pr = a.ca_out_w + (size_t)gw * DIM;
    #pragma unroll
    for (int k = 0; k < 16; ++k) pw[k] = pr[lane + 64 * k];
    float bias = a.ca_out_b[gw];
    for (int t = 0; t < 64; ++t){
      const float* xr = a.vtmp + (size_t)t * DIM;
      #pragma unroll
      for (int k = 0; k < 4; ++k) smA[tid + 256 * k] = ldc(xr + tid + 256 * k);
      __syncthreads();
      float acc = 0.f;
      #pragma unroll
      for (int k = 0; k < 16; ++k) acc = fmaf(pw[k], smA[lane + 64 * k], acc);
      acc = wsum(acc);
      if (lane == 0) stc(a.cac + (size_t)t * DIM + gw, acc + bias);
      __syncthreads();
    }
  }
  ++bep; gsync(a.bar, bep, bid, tid);

  // ---- main weight rows into registers (128 floats/thread)
  float wq[16], wk[16], wv[16], wo[16], f1a[16], f1b[16], f2[32];
  {
    const float* pq = a.sa_in_w + (size_t)gw * DIM;
    const float* pk = a.sa_in_w + (size_t)(DIM + gw) * DIM;
    const float* pv = a.sa_in_w + (size_t)(2 * DIM + gw) * DIM;
    const float* po = a.sa_out_w + (size_t)gw * DIM;
    const float* p1a = a.ff1_w + (size_t)(2 * gw) * DIM;
    const float* p1b = a.ff1_w + (size_t)(2 * gw + 1) * DIM;
    const float* p2 = a.ff2_w + (size_t)gw * 2048;
    #pragma unroll
    for (int k = 0; k < 16; ++k){
      int d = lane + 64 * k;
      wq[k] = pq[d]; wk[k] = pk[d]; wv[k] = pv[d]; wo[k] = po[d];
      f1a[k] = p1a[d]; f1b[k] = p1b[d];
    }
    #pragma unroll
    for (int k = 0; k < 32; ++k) f2[k] = p2[lane + 64 * k];
  }
  const float b_q  = a.sa_in_b[gw];
  const float b_k  = a.sa_in_b[DIM + gw];
  const float b_v  = a.sa_in_b[2 * DIM + gw];
  const float b_o  = a.sa_out_b[gw];
  const float b_1a = a.ff1_b[2 * gw];
  const float b_1b = a.ff1_b[2 * gw + 1];
  const float b_2  = a.ff2_b[gw];
  const float b_vr = a.vr_b[gw];
  float cbv;
  {
    const float* pv = a.vm_w + (size_t)gw * DIM;
    float acc = 0.f;
    #pragma unroll
    for (int k = 0; k < 16; ++k) acc = fmaf(pv[lane + 64 * k], a.vr_b[lane + 64 * k], acc);
    cbv = wsum(acc) + a.vm_b[gw] + a.obj_w[(size_t)gw * 80];
  }

  // running projected-V cache: lane j holds c^h_j = wo_gw[head h] . V_j[head h]
  float c0 = 0.f, c1 = 0.f, c2 = 0.f, c3 = 0.f;

  const bool is_score = (bid < 16);
  const int sc_h  = bid >> 2;
  const int sc_jg = bid & 3;
  const int swid  = bid * 4 + wave;                    // 0..63 for score blocks
  const float sc_slope = 1.0f / (float)(4 << (2 * sc_h));

  for (int i = 0; i < SEQ; ++i){
    const float posf = (float)(i % 30);
    const unsigned ep = (unsigned)(i + 1);
    float remb;

    // ---- S1: stage x = emb[i]+pe[i]; QKV; publish (q),(v) slots; kc row i
    {
      if (i == 0){
        #pragma unroll
        for (int k = 0; k < 4; ++k){
          int d = tid + 256 * k;
          float arg = posf * div4[k];
          float pe = par4[k] ? __cosf(arg) : __sinf(arg);
          smA[d] = a.obj_w[(size_t)d * 80] + pe;
        }
      } else {
        float ev[4];
        poll41(a.lE, tid, ep - 1, ev);
        #pragma unroll
        for (int k = 0; k < 4; ++k){
          int d = tid + 256 * k;
          float arg = posf * div4[k];
          float pe = par4[k] ? __cosf(arg) : __sinf(arg);
          smA[d] = ev[k] + pe;
        }
      }
      __syncthreads();
      remb = smA[gw];                      // residual (= emb+pe at dim gw)
      float aq = 0.f, ak = 0.f, av = 0.f;
      #pragma unroll
      for (int k = 0; k < 16; ++k){
        float x = smA[lane + 64 * k];
        aq = fmaf(wq[k], x, aq);
        ak = fmaf(wk[k], x, ak);
        av = fmaf(wv[k], x, av);
      }
      aq = wsum(aq); ak = wsum(ak); av = wsum(av);
      if (lane == 0){
        stc(a.kc + (size_t)i * DIM + gw, ak + b_k);      // K cache for this+future iters
        asm volatile("s_waitcnt vmcnt(0)" ::: "memory"); // drain kc before publish
        u64* L = a.lS1 + (size_t)gw * LQ;
        stq(L, aq + b_q, ep); stq(L + 1, av + b_v, ep);
      }
    }

    // ---- S2: poll (q,v); c-update; scores (16 blocks); softmax; u slot
    {
      float qv[4], vv[4];
      poll42(a.lS1, tid, ep, qv, vv);
      smC[tid] = qv[0]; smC[tid + 256] = qv[1]; smC[tid + 512] = qv[2]; smC[tid + 768] = qv[3];
      smB[tid] = vv[0]; smB[tid + 256] = vv[1]; smB[tid + 512] = vv[2]; smB[tid + 768] = vv[3];
      __syncthreads();
      // c-update from V row
      float p0 = 0.f, p1 = 0.f, p2 = 0.f, p3 = 0.f;
      #pragma unroll
      for (int k = 0; k < 4; ++k){
        p0 = fmaf(wo[k],      smB[lane + 64 * k],        p0);
        p1 = fmaf(wo[k + 4],  smB[lane + 64 * (k + 4)],  p1);
        p2 = fmaf(wo[k + 8],  smB[lane + 64 * (k + 8)],  p2);
        p3 = fmaf(wo[k + 12], smB[lane + 64 * (k + 12)], p3);
      }
      p0 = wsum(p0); p1 = wsum(p1); p2 = wsum(p2); p3 = wsum(p3);
      if (lane == i){ c0 = p0; c1 = p1; c2 = p2; c3 = p3; }
      // scores (block-uniform branch)
      if (is_score){
        float sj[4];
        #pragma unroll
        for (int jj = 0; jj < 4; ++jj){
          int j = sc_jg * 16 + wave * 4 + jj;
          if (j <= i){
            const float* kr = a.kc + (size_t)j * DIM + sc_h * HDIM;
            float acc = 0.f;
            #pragma unroll
            for (int m = 0; m < 4; ++m)
              acc = fmaf(smC[sc_h * HDIM + m * 64 + lane], ldc(kr + m * 64 + lane), acc);
            acc = wsum(acc);
            sj[jj] = acc * 0.0625f - sc_slope * (float)((i - j) / 30);
          } else sj[jj] = 0.f;
        }
        if (lane == 0){
          u64* L = a.lSC + (size_t)swid * LQ;
          stq(L, sj[0], ep); stq(L + 1, sj[1], ep);
          stq(L + 2, sj[2], ep); stq(L + 3, sj[3], ep);
        }
      }
      if (tid < 64){
        float sv[4];
        poll14(a.lSC + (size_t)tid * LQ, ep, sv);
        int h = tid >> 4;
        int j0 = ((tid >> 2) & 3) * 16 + (tid & 3) * 4;
        scp[h * 64 + j0] = sv[0]; scp[h * 64 + j0 + 1] = sv[1];
        scp[h * 64 + j0 + 2] = sv[2]; scp[h * 64 + j0 + 3] = sv[3];
      }
      __syncthreads();
      // softmax (wave = head; wave owns its scp row)
      {
        const int h = wave;
        float sv = (lane <= i) ? scp[h * 64 + lane] : -3.0e38f;
        float mx = wmax(sv);
        float p = (lane <= i) ? __expf(sv - mx) : 0.f;
        float sum = wsum(p);
        scp[h * 64 + lane] = p / sum;
      }
      __syncthreads();
      float t = scp[lane] * c0 + scp[64 + lane] * c1 + scp[128 + lane] * c2 + scp[192 + lane] * c3;
      t = wsum(t);
      if (lane == 0) stq(a.lU + (size_t)gw * LQ, remb + t + b_o, ep);
    }

    // ---- S3: poll u; ln1 -> +cac -> ln2; ff1 -> h slots
    float x2v;
    {
      float cr[4];
      #pragma unroll
      for (int k = 0; k < 4; ++k) cr[k] = ldc(a.cac + (size_t)i * DIM + tid + 256 * k);
      float uv[4];
      poll41(a.lU, tid, ep, uv);
      smA[tid] = uv[0]; smA[tid + 256] = uv[1]; smA[tid + 512] = uv[2]; smA[tid + 768] = uv[3];
      __syncthreads();
      float sa = 0.f, sb = 0.f;
      #pragma unroll
      for (int k = 0; k < 4; ++k){ float x = smA[tid + 256 * k]; sa += x; sb = fmaf(x, x, sb); }
      float2 r = breduce2(sa, sb, red);
      float mean = r.x * (1.f / 1024.f);
      float var  = r.y * (1.f / 1024.f) - mean * mean;
      float rs = 1.f / sqrtf(var + 1e-5f);
      float tv[4];
      float ta = 0.f, tb = 0.f;
      #pragma unroll
      for (int k = 0; k < 4; ++k){
        int d = tid + 256 * k;
        float x1 = (smA[d] - mean) * rs * a.ln1_g[d] + a.ln1_b[d];
        tv[k] = x1 + cr[k];
        ta += tv[k]; tb = fmaf(tv[k], tv[k], tb);
      }
      float2 r2v = breduce2(ta, tb, red);
      float mean2 = r2v.x * (1.f / 1024.f);
      float var2  = r2v.y * (1.f / 1024.f) - mean2 * mean2;
      float rs2 = 1.f / sqrtf(var2 + 1e-5f);
      #pragma unroll
      for (int k = 0; k < 4; ++k){
        int d = tid + 256 * k;
        smA[d] = (tv[k] - mean2) * rs2 * a.ln2_g[d] + a.ln2_b[d];
      }
      __syncthreads();
      x2v = smA[gw];
      float acc0 = 0.f, acc1 = 0.f;
      #pragma unroll
      for (int k = 0; k < 16; ++k){
        float x = smA[lane + 64 * k];
        acc0 = fmaf(f1a[k], x, acc0);
        acc1 = fmaf(f1b[k], x, acc1);
      }
      acc0 = wsum(acc0); acc1 = wsum(acc1);
      if (lane == 0){
        u64* L = a.lH + (size_t)gw * LQ;
        stq(L, fmaxf(acc0 + b_1a, 0.f), ep);
        stq(L + 1, fmaxf(acc1 + b_1b, 0.f), ep);
      }
    }

    // ---- S4: poll h; ff2 -> w slot ; prefetch vr_w/Cm rows
    float vrr[16], cmr[16];
    {
      const float* pr = a.vr_w + (size_t)gw * DIM;
      const float* pc = a.Cm + (size_t)gw * DIM;
      #pragma unroll
      for (int k = 0; k < 16; ++k){ vrr[k] = pr[lane + 64 * k]; cmr[k] = pc[lane + 64 * k]; }
      float h0[4], h1[4];
      poll42(a.lH, tid, ep, h0, h1);
      smA[2 * tid] = h0[0];           smA[2 * tid + 1] = h1[0];
      smA[2 * (tid + 256)] = h0[1];   smA[2 * (tid + 256) + 1] = h1[1];
      smA[2 * (tid + 512)] = h0[2];   smA[2 * (tid + 512) + 1] = h1[2];
      smA[2 * (tid + 768)] = h0[3];   smA[2 * (tid + 768) + 1] = h1[3];
      __syncthreads();
      float acc = 0.f;
      #pragma unroll
      for (int k = 0; k < 32; ++k) acc = fmaf(f2[k], smA[lane + 64 * k], acc);
      acc = wsum(acc);
      if (lane == 0) stq(a.lW + (size_t)gw * LQ, x2v + acc + b_2, ep);
    }

    // ---- S5: poll w; ln3; out row i; recurrence -> emb slot
    {
      float wvv[4];
      poll41(a.lW, tid, ep, wvv);
      smA[tid] = wvv[0]; smA[tid + 256] = wvv[1]; smA[tid + 512] = wvv[2]; smA[tid + 768] = wvv[3];
      __syncthreads();
      float sa = 0.f, sb = 0.f;
      #pragma unroll
      for (int k = 0; k < 4; ++k){ float x = smA[tid + 256 * k]; sa += x; sb = fmaf(x, x, sb); }
      float2 r = breduce2(sa, sb, red);
      float mean = r.x * (1.f / 1024.f);
      float var  = r.y * (1.f / 1024.f) - mean * mean;
      float rs = 1.f / sqrtf(var + 1e-5f);
      float ov[4];
      #pragma unroll
      for (int k = 0; k < 4; ++k){
        int d = tid + 256 * k;
        ov[k] = (smA[d] - mean) * rs * a.ln3_g[d] + a.ln3_b[d];
      }
      __syncthreads();
      #pragma unroll
      for (int k = 0; k < 4; ++k) smA[tid + 256 * k] = ov[k];
      __syncthreads();
      float ar = 0.f, ac = 0.f;
      #pragma unroll
      for (int k = 0; k < 16; ++k){
        float x = smA[lane + 64 * k];
        ar = fmaf(vrr[k], x, ar);
        ac = fmaf(cmr[k], x, ac);
      }
      ar = wsum(ar); ac = wsum(ac);
      if (lane == 0){
        a.out[(size_t)i * DIM + gw] = ar + b_vr;
        stq(a.lE + (size_t)gw * LQ, ac + cbv, ep);
      }
    }
  }
}

// ---------------- host launcher ----------------
extern "C" void kernel_launch(void* const* d_in, const int* in_sizes, int n_in,
                              void* d_out, int out_size, void* d_ws, size_t ws_size,
                              hipStream_t stream){
  const float* hs       = (const float*)d_in[0];
  const float* hid_w    = (const float*)d_in[1];
  const float* hid_b    = (const float*)d_in[2];
  const float* obj_w    = (const float*)d_in[3];
  const float* sa_in_w  = (const float*)d_in[4];
  const float* sa_in_b  = (const float*)d_in[5];
  const float* sa_out_w = (const float*)d_in[6];
  const float* sa_out_b = (const float*)d_in[7];
  const float* ca_in_w  = (const float*)d_in[8];
  const float* ca_in_b  = (const float*)d_in[9];
  const float* ca_out_w = (const float*)d_in[10];
  const float* ca_out_b = (const float*)d_in[11];
  const float* ln1_g    = (const float*)d_in[12];
  const float* ln1_b    = (const float*)d_in[13];
  const float* ln2_g    = (const float*)d_in[14];
  const float* ln2_b    = (const float*)d_in[15];
  const float* ln3_g    = (const float*)d_in[16];
  const float* ln3_b    = (const float*)d_in[17];
  const float* ff1_w    = (const float*)d_in[18];
  const float* ff1_b    = (const float*)d_in[19];
  const float* ff2_w    = (const float*)d_in[20];
  const float* ff2_b    = (const float*)d_in[21];
  const float* vr_w     = (const float*)d_in[22];
  const float* vr_b     = (const float*)d_in[23];
  const float* vm_w     = (const float*)d_in[24];
  const float* vm_b     = (const float*)d_in[25];

  float* ws = (float*)d_ws;
  float* mem  = ws;                 // 65536
  float* vtmp = ws + 65536;         // 65536
  float* cac  = ws + 131072;        // 65536
  float* kc   = ws + 196608;        // 65536
  float* Cm   = ws + 262144;        // 1048576
  u64* lS1 = (u64*)(ws + 1310720);  // 1024 lines * 16 u64 = 32768 floats
  u64* lU  = (u64*)(ws + 1343488);
  u64* lH  = (u64*)(ws + 1376256);
  u64* lW  = (u64*)(ws + 1409024);
  u64* lE  = (u64*)(ws + 1441792);
  u64* lSC = (u64*)(ws + 1474560);  // 64 lines
  unsigned* bar = (unsigned*)(ws + 1478656);

  // zero all line regions + P-stage barrier slots (re-poison safe)
  hipMemsetAsync((void*)lS1, 0, (size_t)(167936 + 8192) * 4, stream);

  // Cm = vm_w @ vr_w  (folds the two recurrence gemvs)
  matmul_nn_1024<<<dim3(32, 32), 256, 0, stream>>>(vm_w, vr_w, Cm);

  CoopArgs A;
  A.hs = hs; A.hid_w = hid_w; A.hid_b = hid_b;
  A.sa_in_w = sa_in_w; A.sa_in_b = sa_in_b; A.sa_out_w = sa_out_w; A.sa_out_b = sa_out_b;
  A.ca_in_w = ca_in_w; A.ca_in_b = ca_in_b; A.ca_out_w = ca_out_w; A.ca_out_b = ca_out_b;
  A.ln1_g = ln1_g; A.ln1_b = ln1_b; A.ln2_g = ln2_g; A.ln2_b = ln2_b; A.ln3_g = ln3_g; A.ln3_b = ln3_b;
  A.ff1_w = ff1_w; A.ff1_b = ff1_b; A.ff2_w = ff2_w; A.ff2_b = ff2_b;
  A.vr_w = vr_w; A.vr_b = vr_b; A.vm_w = vm_w; A.vm_b = vm_b; A.obj_w = obj_w;
  A.Cm = Cm;
  A.mem = mem; A.vtmp = vtmp; A.cac = cac; A.kc = kc;
  A.lS1 = lS1; A.lU = lU; A.lH = lH; A.lW = lW; A.lE = lE; A.lSC = lSC;
  A.out = (float*)d_out;
  A.bar = bar;

  void* params[1] = { &A };
  hipError_t e = hipLaunchCooperativeKernel((void*)decode_loop, dim3(NBLK), dim3(256), params, 0, stream);
  if (e != hipSuccess){
    decode_loop<<<dim3(NBLK), dim3(256), 0, stream>>>(A);
  }
}

// Round 13
// 2461.143 us; speedup vs baseline: 54.8208x; 1.4690x over previous
//
#include <hip/hip_runtime.h>
#include <math.h>

#define DIM  1024
#define SEQ  64
#define HDIM 256
#define NBLK 256
#define SLOT_STRIDE 32   // 32 u32 = 128 B

// ---------------- wave / block reduction helpers ----------------
__device__ __forceinline__ float wsum(float v){
  v += __shfl_xor(v, 32, 64); v += __shfl_xor(v, 16, 64); v += __shfl_xor(v, 8, 64);
  v += __shfl_xor(v, 4, 64);  v += __shfl_xor(v, 2, 64);  v += __shfl_xor(v, 1, 64);
  return v;
}
__device__ __forceinline__ float wmax(float v){
  v = fmaxf(v, __shfl_xor(v, 32, 64)); v = fmaxf(v, __shfl_xor(v, 16, 64));
  v = fmaxf(v, __shfl_xor(v, 8, 64));  v = fmaxf(v, __shfl_xor(v, 4, 64));
  v = fmaxf(v, __shfl_xor(v, 2, 64));  v = fmaxf(v, __shfl_xor(v, 1, 64));
  return v;
}
__device__ __forceinline__ float2 breduce2(float va, float vb, float* red){
  int tid = threadIdx.x;
  va = wsum(va); vb = wsum(vb);
  if ((tid & 63) == 0){ red[(tid >> 6) * 2] = va; red[(tid >> 6) * 2 + 1] = vb; }
  __syncthreads();
  float ra = red[0] + red[2] + red[4] + red[6];
  float rb = red[1] + red[3] + red[5] + red[7];
  __syncthreads();
  return make_float2(ra, rb);
}

// ---------------- proven device-coherent primitives (R8 chassis) ----------------
__device__ __forceinline__ float ldc(const float* p){
  return __hip_atomic_load(p, __ATOMIC_RELAXED, __HIP_MEMORY_SCOPE_AGENT);
}
__device__ __forceinline__ void stc(float* p, float v){
  __hip_atomic_store(p, v, __ATOMIC_RELAXED, __HIP_MEMORY_SCOPE_AGENT);
}
__device__ __forceinline__ void spin_ge(unsigned* p, unsigned ep){
  unsigned spins = 0;
  while (__hip_atomic_load(p, __ATOMIC_RELAXED, __HIP_MEMORY_SCOPE_AGENT) < ep){
    if (++spins > 100000000u) break;
  }
}
// flat barrier, 128B-padded slots (R8, proven 2.03ms decode / 88MB FETCH)
__device__ __forceinline__ void gsync(unsigned* slots, unsigned ep, int bid, int tid){
  asm volatile("s_waitcnt vmcnt(0)" ::: "memory");
  __syncthreads();
  if (tid == 0)
    __hip_atomic_store(&slots[bid * SLOT_STRIDE], ep, __ATOMIC_RELAXED, __HIP_MEMORY_SCOPE_AGENT);
  spin_ge(&slots[tid * SLOT_STRIDE], ep);
  __syncthreads();
  asm volatile("" ::: "memory");
}

// ---------------- prologue matmuls ----------------
// Cc = A @ B, 1024^3, row-major
__global__ void matmul_nn_1024(const float* __restrict__ A, const float* __restrict__ B,
                               float* __restrict__ Cc){
  __shared__ float As[32][33];
  __shared__ float Bs[32][33];
  int tb = blockIdx.x * 32, ta = blockIdx.y * 32;
  int tx = threadIdx.x & 31, ty = threadIdx.x >> 5;
  float acc[4] = {0.f, 0.f, 0.f, 0.f};
  for (int k0 = 0; k0 < 1024; k0 += 32){
    for (int r = ty; r < 32; r += 8) As[r][tx] = A[(size_t)(ta + r) * 1024 + k0 + tx];
    for (int r = ty; r < 32; r += 8) Bs[r][tx] = B[(size_t)(k0 + r) * 1024 + tb + tx];
    __syncthreads();
    #pragma unroll
    for (int kk = 0; kk < 32; ++kk){
      float bv = Bs[kk][tx];
      #pragma unroll
      for (int m = 0; m < 4; ++m) acc[m] = fmaf(As[ty + 8 * m][kk], bv, acc[m]);
    }
    __syncthreads();
  }
  for (int m = 0; m < 4; ++m) Cc[(size_t)(ta + ty + 8 * m) * 1024 + tb + tx] = acc[m];
}
// W[z] = (sa_in_w + z*1M) @ Cm for z = 0,1,2  (Wq', Wk', Wv')
__global__ void fold3_1024(const float* __restrict__ A0, const float* __restrict__ B,
                           float* __restrict__ W0){
  __shared__ float As[32][33];
  __shared__ float Bs[32][33];
  const float* A = A0 + (size_t)blockIdx.z * 1024 * 1024;
  float* Cc = W0 + (size_t)blockIdx.z * 1024 * 1024;
  int tb = blockIdx.x * 32, ta = blockIdx.y * 32;
  int tx = threadIdx.x & 31, ty = threadIdx.x >> 5;
  float acc[4] = {0.f, 0.f, 0.f, 0.f};
  for (int k0 = 0; k0 < 1024; k0 += 32){
    for (int r = ty; r < 32; r += 8) As[r][tx] = A[(size_t)(ta + r) * 1024 + k0 + tx];
    for (int r = ty; r < 32; r += 8) Bs[r][tx] = B[(size_t)(k0 + r) * 1024 + tb + tx];
    __syncthreads();
    #pragma unroll
    for (int kk = 0; kk < 32; ++kk){
      float bv = Bs[kk][tx];
      #pragma unroll
      for (int m = 0; m < 4; ++m) acc[m] = fmaf(As[ty + 8 * m][kk], bv, acc[m]);
    }
    __syncthreads();
  }
  for (int m = 0; m < 4; ++m) Cc[(size_t)(ta + ty + 8 * m) * 1024 + tb + tx] = acc[m];
}

// ---------------- the persistent autoregressive decode ----------------
struct CoopArgs {
  const float *hs, *hid_w, *hid_b;
  const float *sa_in_w, *sa_in_b, *sa_out_w, *sa_out_b;
  const float *ca_in_w, *ca_in_b, *ca_out_w, *ca_out_b;
  const float *ln1_g, *ln1_b, *ln2_g, *ln2_b, *ln3_g, *ln3_b;
  const float *ff1_w, *ff1_b, *ff2_w, *ff2_b;
  const float *vr_w, *vr_b, *vm_w, *vm_b, *obj_w;
  const float *Cm, *WqF, *WkF, *WvF;
  float *mem, *vtmp, *cac, *kc, *vcur, *q, *u, *hb, *w, *s;
  float *peT, *stylev, *cbvec, *wqpeT, *wkpeT, *wvpeT;
  float *out;
  unsigned *bar, *flags;
};

__global__ void __launch_bounds__(256, 2) decode_loop(CoopArgs a){
  const int tid = threadIdx.x, bid = blockIdx.x;
  const int wave = tid >> 6, lane = tid & 63;
  const int gw = bid * 4 + wave;            // global wave id / row, 0..1023
  __shared__ float smA[2048];
  __shared__ float smB[1024];
  __shared__ float smC[1024];
  __shared__ float scp[256];
  __shared__ float red[8];
  unsigned bep = 0;
  const float NLOG = -9.210340371976184f / 1024.0f;   // -ln(10000)/D

  // ======== P1: mem rows; pe table; style vector ========
  {
    float pw[16];
    const float* pr = a.hid_w + (size_t)gw * DIM;
    #pragma unroll
    for (int k = 0; k < 16; ++k) pw[k] = pr[lane + 64 * k];
    float bias = a.hid_b[gw];
    for (int t = 0; t < 64; ++t){
      const float* xr = a.hs + (size_t)t * DIM;
      float acc = 0.f;
      #pragma unroll
      for (int k = 0; k < 16; ++k) acc = fmaf(pw[k], xr[lane + 64 * k], acc);
      acc = wsum(acc);
      if (lane == 0) stc(a.mem + (size_t)t * DIM + gw, acc + bias);
    }
    if (bid < 30){
      int p = bid;
      for (int d = tid; d < DIM; d += 256){
        float dv = __expf((float)(2 * (d >> 1)) * NLOG);
        float arg = (float)p * dv;
        stc(a.peT + (size_t)p * DIM + d, (d & 1) ? cosf(arg) : sinf(arg));
      }
    } else if (bid == 30){
      for (int d = tid; d < DIM; d += 256) stc(a.stylev + d, a.obj_w[(size_t)d * 80]);
    }
  }
  ++bep; gsync(a.bar, bep, bid, tid);

  // ======== P2: vtmp rows; cb vector ========
  float cbv;
  {
    const float* pv = a.vm_w + (size_t)gw * DIM;
    float acc = 0.f;
    #pragma unroll
    for (int k = 0; k < 16; ++k) acc = fmaf(pv[lane + 64 * k], a.vr_b[lane + 64 * k], acc);
    acc = wsum(acc);
    cbv = acc + a.vm_b[gw] + ldc(a.stylev + gw);
    if (lane == 0) stc(a.cbvec + gw, cbv);
  }
  {
    float pw[16];
    const float* pr = a.ca_in_w + (size_t)(2 * DIM + gw) * DIM;
    #pragma unroll
    for (int k = 0; k < 16; ++k) pw[k] = pr[lane + 64 * k];
    float bias = a.ca_in_b[2 * DIM + gw];
    for (int t = 0; t < 64; ++t){
      const float* xr = a.mem + (size_t)t * DIM;
      #pragma unroll
      for (int k = 0; k < 4; ++k) smA[tid + 256 * k] = ldc(xr + tid + 256 * k);
      __syncthreads();
      float acc = 0.f;
      #pragma unroll
      for (int k = 0; k < 16; ++k) acc = fmaf(pw[k], smA[lane + 64 * k], acc);
      acc = wsum(acc);
      if (lane == 0) stc(a.vtmp + (size_t)t * DIM + gw, acc + bias);
      __syncthreads();
    }
  }
  ++bep; gsync(a.bar, bep, bid, tid);

  // ======== P3: cac rows ========
  {
    float pw[16];
    const float* pr = a.ca_out_w + (size_t)gw * DIM;
    #pragma unroll
    for (int k = 0; k < 16; ++k) pw[k] = pr[lane + 64 * k];
    float bias = a.ca_out_b[gw];
    for (int t = 0; t < 64; ++t){
      const float* xr = a.vtmp + (size_t)t * DIM;
      #pragma unroll
      for (int k = 0; k < 4; ++k) smA[tid + 256 * k] = ldc(xr + tid + 256 * k);
      __syncthreads();
      float acc = 0.f;
      #pragma unroll
      for (int k = 0; k < 16; ++k) acc = fmaf(pw[k], smA[lane + 64 * k], acc);
      acc = wsum(acc);
      if (lane == 0) stc(a.cac + (size_t)t * DIM + gw, acc + bias);
      __syncthreads();
    }
  }
  ++bep; gsync(a.bar, bep, bid, tid);

  // ======== PB: per-row QKV constants: W.cb, W.style, W.pe[p] tables ========
  float aqcb, akcb, avcb, aq0, ak0, av0;
  {
    float wqr[16], wkr[16], wvr[16];
    const float* pq = a.sa_in_w + (size_t)gw * DIM;
    const float* pk = a.sa_in_w + (size_t)(DIM + gw) * DIM;
    const float* pv = a.sa_in_w + (size_t)(2 * DIM + gw) * DIM;
    #pragma unroll
    for (int k = 0; k < 16; ++k){
      int d = lane + 64 * k;
      wqr[k] = pq[d]; wkr[k] = pk[d]; wvr[k] = pv[d];
    }
    const float b_q = a.sa_in_b[gw];
    const float b_k = a.sa_in_b[DIM + gw];
    const float b_v = a.sa_in_b[2 * DIM + gw];
    // W.cb
    #pragma unroll
    for (int k = 0; k < 4; ++k) smA[tid + 256 * k] = ldc(a.cbvec + tid + 256 * k);
    __syncthreads();
    float dq = 0.f, dk = 0.f, dv = 0.f;
    #pragma unroll
    for (int k = 0; k < 16; ++k){
      float x = smA[lane + 64 * k];
      dq = fmaf(wqr[k], x, dq); dk = fmaf(wkr[k], x, dk); dv = fmaf(wvr[k], x, dv);
    }
    aqcb = wsum(dq) + b_q; akcb = wsum(dk) + b_k; avcb = wsum(dv) + b_v;
    __syncthreads();
    // W.style
    #pragma unroll
    for (int k = 0; k < 4; ++k) smA[tid + 256 * k] = ldc(a.stylev + tid + 256 * k);
    __syncthreads();
    float sq = 0.f, sk = 0.f, sv = 0.f;
    #pragma unroll
    for (int k = 0; k < 16; ++k){
      float x = smA[lane + 64 * k];
      sq = fmaf(wqr[k], x, sq); sk = fmaf(wkr[k], x, sk); sv = fmaf(wvr[k], x, sv);
    }
    sq = wsum(sq); sk = wsum(sk); sv = wsum(sv);
    __syncthreads();
    // W.pe[p] tables
    float pq0 = 0.f, pk0 = 0.f, pv0 = 0.f;
    for (int p = 0; p < 30; ++p){
      #pragma unroll
      for (int k = 0; k < 4; ++k) smA[tid + 256 * k] = ldc(a.peT + (size_t)p * DIM + tid + 256 * k);
      __syncthreads();
      float tq = 0.f, tk = 0.f, tv = 0.f;
      #pragma unroll
      for (int k = 0; k < 16; ++k){
        float x = smA[lane + 64 * k];
        tq = fmaf(wqr[k], x, tq); tk = fmaf(wkr[k], x, tk); tv = fmaf(wvr[k], x, tv);
      }
      tq = wsum(tq); tk = wsum(tk); tv = wsum(tv);
      if (lane == 0){
        stc(a.wqpeT + (size_t)p * DIM + gw, tq);
        stc(a.wkpeT + (size_t)p * DIM + gw, tk);
        stc(a.wvpeT + (size_t)p * DIM + gw, tv);
      }
      if (p == 0){ pq0 = tq; pk0 = tk; pv0 = tv; }
      __syncthreads();
    }
    aq0 = sq + pq0 + b_q; ak0 = sk + pk0 + b_k; av0 = sv + pv0 + b_v;
  }
  ++bep; gsync(a.bar, bep, bid, tid);

  // ---- preload folded/main weight rows (128 floats/thread, as R8)
  float fq[16], fk[16], fv[16], wo[16], f1a[16], f1b[16], f2[32];
  {
    const float* pq = a.WqF + (size_t)gw * DIM;
    const float* pk = a.WkF + (size_t)gw * DIM;
    const float* pv = a.WvF + (size_t)gw * DIM;
    const float* po = a.sa_out_w + (size_t)gw * DIM;
    const float* p1a = a.ff1_w + (size_t)(2 * gw) * DIM;
    const float* p1b = a.ff1_w + (size_t)(2 * gw + 1) * DIM;
    const float* p2 = a.ff2_w + (size_t)gw * 2048;
    #pragma unroll
    for (int k = 0; k < 16; ++k){
      int d = lane + 64 * k;
      fq[k] = pq[d]; fk[k] = pk[d]; fv[k] = pv[d]; wo[k] = po[d];
      f1a[k] = p1a[d]; f1b[k] = p1b[d];
    }
    #pragma unroll
    for (int k = 0; k < 32; ++k) f2[k] = p2[lane + 64 * k];
  }
  const float b_o  = a.sa_out_b[gw];
  const float b_1a = a.ff1_b[2 * gw];
  const float b_1b = a.ff1_b[2 * gw + 1];
  const float b_2  = a.ff2_b[gw];
  const float b_vr = a.vr_b[gw];

  // running projected-V cache
  float c0 = 0.f, c1 = 0.f, c2 = 0.f, c3 = 0.f;
  const bool is_score = (bid < 16);
  const int sc_h  = bid >> 2;
  const int sc_jg = bid & 3;
  const float sc_slope = 1.0f / (float)(4 << (2 * sc_h));

  // ======== MS0: publish q/k/v for i=0; residual x0[gw] ========
  float xres;
  if (lane == 0){
    stc(a.q + gw, aq0);
    stc(a.kc + gw, ak0);
    stc(a.vcur + gw, av0);
  }
  xres = a.obj_w[(size_t)gw * 80] + ldc(a.peT + gw);
  ++bep; gsync(a.bar, bep, bid, tid);

  float vrr[16], cmr[16];
  for (int i = 0; i < SEQ; ++i){
    const unsigned ep = (unsigned)(i + 1);

    // ---- MS2: attention -> u  (c-update || scores -> flags -> softmax)
    {
      #pragma unroll
      for (int k = 0; k < 4; ++k){
        smB[tid + 256 * k] = ldc(a.vcur + tid + 256 * k);
        smC[tid + 256 * k] = ldc(a.q + tid + 256 * k);
      }
      __syncthreads();
      float p0 = 0.f, p1 = 0.f, p2 = 0.f, p3 = 0.f;
      #pragma unroll
      for (int k = 0; k < 4; ++k){
        p0 = fmaf(wo[k],      smB[lane + 64 * k],        p0);
        p1 = fmaf(wo[k + 4],  smB[lane + 64 * (k + 4)],  p1);
        p2 = fmaf(wo[k + 8],  smB[lane + 64 * (k + 8)],  p2);
        p3 = fmaf(wo[k + 12], smB[lane + 64 * (k + 12)], p3);
      }
      p0 = wsum(p0); p1 = wsum(p1); p2 = wsum(p2); p3 = wsum(p3);
      if (lane == i){ c0 = p0; c1 = p1; c2 = p2; c3 = p3; }
      if (is_score){
        #pragma unroll
        for (int jj = 0; jj < 4; ++jj){
          int j = sc_jg * 16 + wave * 4 + jj;
          if (j <= i){
            const float* kr = a.kc + (size_t)j * DIM + sc_h * HDIM;
            float acc = 0.f;
            #pragma unroll
            for (int m = 0; m < 4; ++m)
              acc = fmaf(smC[sc_h * HDIM + m * 64 + lane], ldc(kr + m * 64 + lane), acc);
            acc = wsum(acc);
            if (lane == 0)
              stc(a.s + sc_h * 64 + j, acc * 0.0625f - sc_slope * (float)((i - j) / 30));
          }
        }
        asm volatile("s_waitcnt vmcnt(0)" ::: "memory");
        __syncthreads();
        if (tid == 0)
          __hip_atomic_store(&a.flags[bid * SLOT_STRIDE], ep,
                             __ATOMIC_RELAXED, __HIP_MEMORY_SCOPE_AGENT);
      }
      if (tid < 16) spin_ge(&a.flags[tid * SLOT_STRIDE], ep);
      __syncthreads();
      {
        const int h = wave;
        float sv = (lane <= i) ? ldc(a.s + h * 64 + lane) : -3.0e38f;
        float mx = wmax(sv);
        float p = (lane <= i) ? __expf(sv - mx) : 0.f;
        float sum = wsum(p);
        scp[h * 64 + lane] = p / sum;
      }
      __syncthreads();
      float t = scp[lane] * c0 + scp[64 + lane] * c1 + scp[128 + lane] * c2 + scp[192 + lane] * c3;
      t = wsum(t);
      if (lane == 0) stc(a.u + gw, xres + t + b_o);
      __syncthreads();
    }
    ++bep; gsync(a.bar, bep, bid, tid);

    // ---- MS3: ln1 -> +cac -> ln2 ; ff1 -> hb
    float x2v;
    {
      float cr[4];
      #pragma unroll
      for (int k = 0; k < 4; ++k) cr[k] = ldc(a.cac + (size_t)i * DIM + tid + 256 * k);
      #pragma unroll
      for (int k = 0; k < 4; ++k) smA[tid + 256 * k] = ldc(a.u + tid + 256 * k);
      __syncthreads();
      float sa = 0.f, sb = 0.f;
      #pragma unroll
      for (int k = 0; k < 4; ++k){ float x = smA[tid + 256 * k]; sa += x; sb = fmaf(x, x, sb); }
      float2 r = breduce2(sa, sb, red);
      float mean = r.x * (1.f / 1024.f);
      float var  = r.y * (1.f / 1024.f) - mean * mean;
      float rs = 1.f / sqrtf(var + 1e-5f);
      float tv[4];
      float ta = 0.f, tb = 0.f;
      #pragma unroll
      for (int k = 0; k < 4; ++k){
        int d = tid + 256 * k;
        float x1 = (smA[d] - mean) * rs * a.ln1_g[d] + a.ln1_b[d];
        tv[k] = x1 + cr[k];
        ta += tv[k]; tb = fmaf(tv[k], tv[k], tb);
      }
      float2 r2v = breduce2(ta, tb, red);
      float mean2 = r2v.x * (1.f / 1024.f);
      float var2  = r2v.y * (1.f / 1024.f) - mean2 * mean2;
      float rs2 = 1.f / sqrtf(var2 + 1e-5f);
      #pragma unroll
      for (int k = 0; k < 4; ++k){
        int d = tid + 256 * k;
        smA[d] = (tv[k] - mean2) * rs2 * a.ln2_g[d] + a.ln2_b[d];
      }
      __syncthreads();
      x2v = smA[gw];
      float acc0 = 0.f, acc1 = 0.f;
      #pragma unroll
      for (int k = 0; k < 16; ++k){
        float x = smA[lane + 64 * k];
        acc0 = fmaf(f1a[k], x, acc0);
        acc1 = fmaf(f1b[k], x, acc1);
      }
      acc0 = wsum(acc0); acc1 = wsum(acc1);
      if (lane == 0){
        stc(a.hb + 2 * gw,     fmaxf(acc0 + b_1a, 0.f));
        stc(a.hb + 2 * gw + 1, fmaxf(acc1 + b_1b, 0.f));
      }
      __syncthreads();
    }
    ++bep; gsync(a.bar, bep, bid, tid);

    // ---- MS4: ff2 -> w ; prefetch vr_w/Cm rows
    {
      const float* pr = a.vr_w + (size_t)gw * DIM;
      const float* pc = a.Cm + (size_t)gw * DIM;
      #pragma unroll
      for (int k = 0; k < 16; ++k){ vrr[k] = pr[lane + 64 * k]; cmr[k] = pc[lane + 64 * k]; }
      #pragma unroll
      for (int k = 0; k < 8; ++k) smA[tid + 256 * k] = ldc(a.hb + tid + 256 * k);
      __syncthreads();
      float acc = 0.f;
      #pragma unroll
      for (int k = 0; k < 32; ++k) acc = fmaf(f2[k], smA[lane + 64 * k], acc);
      acc = wsum(acc);
      if (lane == 0) stc(a.w + gw, x2v + acc + b_2);
      __syncthreads();
    }
    ++bep; gsync(a.bar, bep, bid, tid);

    // ---- MS1': ln3 -> y ; out row i ; folded QKV + residual for i+1
    {
      #pragma unroll
      for (int k = 0; k < 4; ++k) smA[tid + 256 * k] = ldc(a.w + tid + 256 * k);
      __syncthreads();
      float sa = 0.f, sb = 0.f;
      #pragma unroll
      for (int k = 0; k < 4; ++k){ float x = smA[tid + 256 * k]; sa += x; sb = fmaf(x, x, sb); }
      float2 r = breduce2(sa, sb, red);
      float mean = r.x * (1.f / 1024.f);
      float var  = r.y * (1.f / 1024.f) - mean * mean;
      float rs = 1.f / sqrtf(var + 1e-5f);
      float ov[4];
      #pragma unroll
      for (int k = 0; k < 4; ++k){
        int d = tid + 256 * k;
        ov[k] = (smA[d] - mean) * rs * a.ln3_g[d] + a.ln3_b[d];
      }
      __syncthreads();
      #pragma unroll
      for (int k = 0; k < 4; ++k) smA[tid + 256 * k] = ov[k];
      __syncthreads();
      float ar = 0.f, ac = 0.f, aqn = 0.f, akn = 0.f, avn = 0.f;
      #pragma unroll
      for (int k = 0; k < 16; ++k){
        float x = smA[lane + 64 * k];
        ar  = fmaf(vrr[k], x, ar);
        ac  = fmaf(cmr[k], x, ac);
        aqn = fmaf(fq[k], x, aqn);
        akn = fmaf(fk[k], x, akn);
        avn = fmaf(fv[k], x, avn);
      }
      ar = wsum(ar); ac = wsum(ac);
      aqn = wsum(aqn); akn = wsum(akn); avn = wsum(avn);
      if (lane == 0) a.out[(size_t)i * DIM + gw] = ar + b_vr;
      if (i < SEQ - 1){
        int pn = (i + 1) % 30;
        if (lane == 0){
          float tq = ldc(a.wqpeT + (size_t)pn * DIM + gw);
          float tk = ldc(a.wkpeT + (size_t)pn * DIM + gw);
          float tv = ldc(a.wvpeT + (size_t)pn * DIM + gw);
          stc(a.q + gw, aqn + aqcb + tq);
          stc(a.kc + (size_t)(i + 1) * DIM + gw, akn + akcb + tk);
          stc(a.vcur + gw, avn + avcb + tv);
        }
        xres = ac + cbv + ldc(a.peT + (size_t)pn * DIM + gw);
        __syncthreads();
        ++bep; gsync(a.bar, bep, bid, tid);
      }
    }
  }
}

// ---------------- host launcher ----------------
extern "C" void kernel_launch(void* const* d_in, const int* in_sizes, int n_in,
                              void* d_out, int out_size, void* d_ws, size_t ws_size,
                              hipStream_t stream){
  const float* hs       = (const float*)d_in[0];
  const float* hid_w    = (const float*)d_in[1];
  const float* hid_b    = (const float*)d_in[2];
  const float* obj_w    = (const float*)d_in[3];
  const float* sa_in_w  = (const float*)d_in[4];
  const float* sa_in_b  = (const float*)d_in[5];
  const float* sa_out_w = (const float*)d_in[6];
  const float* sa_out_b = (const float*)d_in[7];
  const float* ca_in_w  = (const float*)d_in[8];
  const float* ca_in_b  = (const float*)d_in[9];
  const float* ca_out_w = (const float*)d_in[10];
  const float* ca_out_b = (const float*)d_in[11];
  const float* ln1_g    = (const float*)d_in[12];
  const float* ln1_b    = (const float*)d_in[13];
  const float* ln2_g    = (const float*)d_in[14];
  const float* ln2_b    = (const float*)d_in[15];
  const float* ln3_g    = (const float*)d_in[16];
  const float* ln3_b    = (const float*)d_in[17];
  const float* ff1_w    = (const float*)d_in[18];
  const float* ff1_b    = (const float*)d_in[19];
  const float* ff2_w    = (const float*)d_in[20];
  const float* ff2_b    = (const float*)d_in[21];
  const float* vr_w     = (const float*)d_in[22];
  const float* vr_b     = (const float*)d_in[23];
  const float* vm_w     = (const float*)d_in[24];
  const float* vm_b     = (const float*)d_in[25];

  float* ws = (float*)d_ws;
  float* mem    = ws;                 // 65536
  float* vtmp   = ws + 65536;         // 65536
  float* cac    = ws + 131072;        // 65536
  float* kc     = ws + 196608;        // 65536
  float* vcur   = ws + 262144;        // 1024
  float* q      = ws + 263168;        // 1024
  float* u      = ws + 264192;        // 1024
  float* hb     = ws + 265216;        // 2048
  float* wv     = ws + 267264;        // 1024
  float* sbuf   = ws + 268288;        // 1024
  float* peT    = ws + 269312;        // 30720
  float* stylev = ws + 300032;        // 1024
  float* cbvec  = ws + 301056;        // 1024
  float* wqpeT  = ws + 302080;        // 30720
  float* wkpeT  = ws + 332800;        // 30720
  float* wvpeT  = ws + 363520;        // 30720
  unsigned* bar   = (unsigned*)(ws + 394240);   // 256*32 u32 = 32KB
  unsigned* flags = bar + 256 * SLOT_STRIDE;    // 16*32 u32 = 2KB
  float* Cm     = ws + 409600;        // 1048576
  float* WqF    = ws + 1458176;       // 1048576 (Wq@Cm)
  float* WkF    = ws + 2506752;       // 1048576
  float* WvF    = ws + 3555328;       // 1048576  -> end 4603904 floats (18.4MB)

  // zero barrier slots + flags (re-poison safe)
  hipMemsetAsync((void*)bar, 0, (256 + 16) * SLOT_STRIDE * 4, stream);

  // Cm = vm_w @ vr_w ; W{q,k,v}F = sa_in_w[z] @ Cm
  matmul_nn_1024<<<dim3(32, 32), 256, 0, stream>>>(vm_w, vr_w, Cm);
  fold3_1024<<<dim3(32, 32, 3), 256, 0, stream>>>(sa_in_w, Cm, WqF);

  CoopArgs A;
  A.hs = hs; A.hid_w = hid_w; A.hid_b = hid_b;
  A.sa_in_w = sa_in_w; A.sa_in_b = sa_in_b; A.sa_out_w = sa_out_w; A.sa_out_b = sa_out_b;
  A.ca_in_w = ca_in_w; A.ca_in_b = ca_in_b; A.ca_out_w = ca_out_w; A.ca_out_b = ca_out_b;
  A.ln1_g = ln1_g; A.ln1_b = ln1_b; A.ln2_g = ln2_g; A.ln2_b = ln2_b; A.ln3_g = ln3_g; A.ln3_b = ln3_b;
  A.ff1_w = ff1_w; A.ff1_b = ff1_b; A.ff2_w = ff2_w; A.ff2_b = ff2_b;
  A.vr_w = vr_w; A.vr_b = vr_b; A.vm_w = vm_w; A.vm_b = vm_b; A.obj_w = obj_w;
  A.Cm = Cm; A.WqF = WqF; A.WkF = WkF; A.WvF = WvF;
  A.mem = mem; A.vtmp = vtmp; A.cac = cac; A.kc = kc; A.vcur = vcur;
  A.q = q; A.u = u; A.hb = hb; A.w = wv; A.s = sbuf;
  A.peT = peT; A.stylev = stylev; A.cbvec = cbvec;
  A.wqpeT = wqpeT; A.wkpeT = wkpeT; A.wvpeT = wvpeT;
  A.out = (float*)d_out;
  A.bar = bar; A.flags = flags;

  void* params[1] = { &A };
  hipError_t e = hipLaunchCooperativeKernel((void*)decode_loop, dim3(NBLK), dim3(256), params, 0, stream);
  if (e != hipSuccess){
    decode_loop<<<dim3(NBLK), dim3(256), 0, stream>>>(A);
  }
}

// Round 14
// 2266.508 us; speedup vs baseline: 59.5285x; 1.0859x over previous
//
#include <hip/hip_runtime.h>
#include <math.h>

#define DIM  1024
#define SEQ  64
#define HDIM 256
#define NBLK 256
#define SLOT_STRIDE 32   // 32 u32 = 128 B

// ---------------- wave / block reduction helpers ----------------
__device__ __forceinline__ float wsum(float v){
  v += __shfl_xor(v, 32, 64); v += __shfl_xor(v, 16, 64); v += __shfl_xor(v, 8, 64);
  v += __shfl_xor(v, 4, 64);  v += __shfl_xor(v, 2, 64);  v += __shfl_xor(v, 1, 64);
  return v;
}
__device__ __forceinline__ float wmax(float v){
  v = fmaxf(v, __shfl_xor(v, 32, 64)); v = fmaxf(v, __shfl_xor(v, 16, 64));
  v = fmaxf(v, __shfl_xor(v, 8, 64));  v = fmaxf(v, __shfl_xor(v, 4, 64));
  v = fmaxf(v, __shfl_xor(v, 2, 64));  v = fmaxf(v, __shfl_xor(v, 1, 64));
  return v;
}
__device__ __forceinline__ float2 breduce2(float va, float vb, float* red){
  int tid = threadIdx.x;
  va = wsum(va); vb = wsum(vb);
  if ((tid & 63) == 0){ red[(tid >> 6) * 2] = va; red[(tid >> 6) * 2 + 1] = vb; }
  __syncthreads();
  float ra = red[0] + red[2] + red[4] + red[6];
  float rb = red[1] + red[3] + red[5] + red[7];
  __syncthreads();
  return make_float2(ra, rb);
}

// ---------------- proven device-coherent primitives (R8 chassis) ----------------
__device__ __forceinline__ float ldc(const float* p){
  return __hip_atomic_load(p, __ATOMIC_RELAXED, __HIP_MEMORY_SCOPE_AGENT);
}
__device__ __forceinline__ void stc(float* p, float v){
  __hip_atomic_store(p, v, __ATOMIC_RELAXED, __HIP_MEMORY_SCOPE_AGENT);
}
__device__ __forceinline__ void sta(unsigned* p, unsigned v){
  __hip_atomic_store(p, v, __ATOMIC_RELAXED, __HIP_MEMORY_SCOPE_AGENT);
}
__device__ __forceinline__ void spin_ge(unsigned* p, unsigned ep){
  unsigned spins = 0;
  while (__hip_atomic_load(p, __ATOMIC_RELAXED, __HIP_MEMORY_SCOPE_AGENT) < ep){
    __builtin_amdgcn_s_sleep(1);     // backoff: cut LLC poll-storm contention
    if (++spins > 100000000u) break;
  }
}

// ---- hierarchical contention-free barrier ----
// Flat barrier problem: slot line b is polled by 1 thread of EVERY block (256
// readers/line, 65K outstanding polls) -> the poll storm delays the arrival
// stores themselves. Fix: blocks 240..255 aggregate 16 slots each (1 reader
// per slot line), publish group-flag replicated x8; everyone polls the 16
// group flags at replica bid&7 (32 readers/line).
// Layout in bar (128B lines): [0,256) arrival slots; [256,384) gflag[g][r]
// at line 256+g*8+r; [384,512) score flags scfl[s][r] at line 384+s*8+r.
__device__ __forceinline__ void gsync(unsigned* bar, unsigned ep, int bid, int tid){
  unsigned* slots = bar;
  unsigned* gfl   = bar + 256 * SLOT_STRIDE;
  asm volatile("s_waitcnt vmcnt(0)" ::: "memory");
  __syncthreads();
  if (tid == 0) sta(&slots[bid * SLOT_STRIDE], ep);
  if (bid >= 240){
    int g = bid - 240;
    if (tid < 16) spin_ge(&slots[(g * 16 + tid) * SLOT_STRIDE], ep);
    __syncthreads();
    if (tid < 8) sta(&gfl[(g * 8 + tid) * SLOT_STRIDE], ep);
  }
  if (tid < 16) spin_ge(&gfl[(tid * 8 + (bid & 7)) * SLOT_STRIDE], ep);
  __syncthreads();
  asm volatile("" ::: "memory");
}

// ---------------- fast prologue matmul: 64x64 tile, 4x4 per thread ----------------
__global__ void mm1024(const float* __restrict__ A0, const float* __restrict__ B,
                       float* __restrict__ C0, size_t Astride, size_t Cstride){
  const float* A = A0 + (size_t)blockIdx.z * Astride;
  float* C = C0 + (size_t)blockIdx.z * Cstride;
  __shared__ float As[16][65];   // As[kk][m]
  __shared__ float Bs[16][65];   // Bs[kk][n]
  int ta = blockIdx.y * 64, tb = blockIdx.x * 64;
  int tx = threadIdx.x & 15, ty = threadIdx.x >> 4;   // 16x16 threads
  float acc[4][4] = {};
  for (int k0 = 0; k0 < 1024; k0 += 16){
    #pragma unroll
    for (int j = 0; j < 4; ++j)
      As[tx][ty * 4 + j] = A[(size_t)(ta + ty * 4 + j) * 1024 + k0 + tx];
    {
      const float4 bv = *(const float4*)&B[(size_t)(k0 + ty) * 1024 + tb + tx * 4];
      Bs[ty][tx * 4]     = bv.x; Bs[ty][tx * 4 + 1] = bv.y;
      Bs[ty][tx * 4 + 2] = bv.z; Bs[ty][tx * 4 + 3] = bv.w;
    }
    __syncthreads();
    #pragma unroll
    for (int kk = 0; kk < 16; ++kk){
      float av[4], bv[4];
      #pragma unroll
      for (int m = 0; m < 4; ++m) av[m] = As[kk][ty * 4 + m];
      #pragma unroll
      for (int n = 0; n < 4; ++n) bv[n] = Bs[kk][tx * 4 + n];
      #pragma unroll
      for (int m = 0; m < 4; ++m)
        #pragma unroll
        for (int n = 0; n < 4; ++n) acc[m][n] = fmaf(av[m], bv[n], acc[m][n]);
    }
    __syncthreads();
  }
  #pragma unroll
  for (int m = 0; m < 4; ++m){
    float4 ov = { acc[m][0], acc[m][1], acc[m][2], acc[m][3] };
    *(float4*)&C[(size_t)(ta + ty * 4 + m) * 1024 + tb + tx * 4] = ov;
  }
}

// ---------------- the persistent autoregressive decode ----------------
struct CoopArgs {
  const float *hs, *hid_w, *hid_b;
  const float *sa_in_w, *sa_in_b, *sa_out_w, *sa_out_b;
  const float *ca_in_w, *ca_in_b, *ca_out_w, *ca_out_b;
  const float *ln1_g, *ln1_b, *ln2_g, *ln2_b, *ln3_g, *ln3_b;
  const float *ff1_w, *ff1_b, *ff2_w, *ff2_b;
  const float *vr_w, *vr_b, *vm_w, *vm_b, *obj_w;
  const float *Cm, *WqF, *WkF, *WvF;
  float *mem, *vtmp, *cac, *kc, *vcur, *q, *u, *hb, *w, *s;
  float *peT, *stylev, *cbvec, *wqpeT, *wkpeT, *wvpeT;
  float *out;
  unsigned *bar, *flags;   // flags = scfl base (16 flags x 8 replicas)
};

__global__ void __launch_bounds__(256, 2) decode_loop(CoopArgs a){
  const int tid = threadIdx.x, bid = blockIdx.x;
  const int wave = tid >> 6, lane = tid & 63;
  const int gw = bid * 4 + wave;            // global wave id / row, 0..1023
  __shared__ float smA[2048];
  __shared__ float smB[1024];
  __shared__ float smC[1024];
  __shared__ float scp[256];
  __shared__ float red[8];
  unsigned bep = 0;
  const float NLOG = -9.210340371976184f / 1024.0f;   // -ln(10000)/D

  // ======== P1: mem rows; pe table; style vector ========
  {
    float pw[16];
    const float* pr = a.hid_w + (size_t)gw * DIM;
    #pragma unroll
    for (int k = 0; k < 16; ++k) pw[k] = pr[lane + 64 * k];
    float bias = a.hid_b[gw];
    for (int t = 0; t < 64; ++t){
      const float* xr = a.hs + (size_t)t * DIM;
      float acc = 0.f;
      #pragma unroll
      for (int k = 0; k < 16; ++k) acc = fmaf(pw[k], xr[lane + 64 * k], acc);
      acc = wsum(acc);
      if (lane == 0) stc(a.mem + (size_t)t * DIM + gw, acc + bias);
    }
    if (bid < 30){
      int p = bid;
      for (int d = tid; d < DIM; d += 256){
        float dv = __expf((float)(2 * (d >> 1)) * NLOG);
        float arg = (float)p * dv;
        stc(a.peT + (size_t)p * DIM + d, (d & 1) ? cosf(arg) : sinf(arg));
      }
    } else if (bid == 30){
      for (int d = tid; d < DIM; d += 256) stc(a.stylev + d, a.obj_w[(size_t)d * 80]);
    }
  }
  ++bep; gsync(a.bar, bep, bid, tid);

  // ======== P2: vtmp rows; cb vector ========
  float cbv;
  {
    const float* pv = a.vm_w + (size_t)gw * DIM;
    float acc = 0.f;
    #pragma unroll
    for (int k = 0; k < 16; ++k) acc = fmaf(pv[lane + 64 * k], a.vr_b[lane + 64 * k], acc);
    acc = wsum(acc);
    cbv = acc + a.vm_b[gw] + ldc(a.stylev + gw);
    if (lane == 0) stc(a.cbvec + gw, cbv);
  }
  {
    float pw[16];
    const float* pr = a.ca_in_w + (size_t)(2 * DIM + gw) * DIM;
    #pragma unroll
    for (int k = 0; k < 16; ++k) pw[k] = pr[lane + 64 * k];
    float bias = a.ca_in_b[2 * DIM + gw];
    for (int t = 0; t < 64; ++t){
      const float* xr = a.mem + (size_t)t * DIM;
      #pragma unroll
      for (int k = 0; k < 4; ++k) smA[tid + 256 * k] = ldc(xr + tid + 256 * k);
      __syncthreads();
      float acc = 0.f;
      #pragma unroll
      for (int k = 0; k < 16; ++k) acc = fmaf(pw[k], smA[lane + 64 * k], acc);
      acc = wsum(acc);
      if (lane == 0) stc(a.vtmp + (size_t)t * DIM + gw, acc + bias);
      __syncthreads();
    }
  }
  ++bep; gsync(a.bar, bep, bid, tid);

  // ======== P3: cac rows ========
  {
    float pw[16];
    const float* pr = a.ca_out_w + (size_t)gw * DIM;
    #pragma unroll
    for (int k = 0; k < 16; ++k) pw[k] = pr[lane + 64 * k];
    float bias = a.ca_out_b[gw];
    for (int t = 0; t < 64; ++t){
      const float* xr = a.vtmp + (size_t)t * DIM;
      #pragma unroll
      for (int k = 0; k < 4; ++k) smA[tid + 256 * k] = ldc(xr + tid + 256 * k);
      __syncthreads();
      float acc = 0.f;
      #pragma unroll
      for (int k = 0; k < 16; ++k) acc = fmaf(pw[k], smA[lane + 64 * k], acc);
      acc = wsum(acc);
      if (lane == 0) stc(a.cac + (size_t)t * DIM + gw, acc + bias);
      __syncthreads();
    }
  }
  ++bep; gsync(a.bar, bep, bid, tid);

  // ======== PB: per-row QKV constants: W.cb, W.style, W.pe[p] tables ========
  float aqcb, akcb, avcb, aq0, ak0, av0;
  {
    float wqr[16], wkr[16], wvr[16];
    const float* pq = a.sa_in_w + (size_t)gw * DIM;
    const float* pk = a.sa_in_w + (size_t)(DIM + gw) * DIM;
    const float* pv = a.sa_in_w + (size_t)(2 * DIM + gw) * DIM;
    #pragma unroll
    for (int k = 0; k < 16; ++k){
      int d = lane + 64 * k;
      wqr[k] = pq[d]; wkr[k] = pk[d]; wvr[k] = pv[d];
    }
    const float b_q = a.sa_in_b[gw];
    const float b_k = a.sa_in_b[DIM + gw];
    const float b_v = a.sa_in_b[2 * DIM + gw];
    #pragma unroll
    for (int k = 0; k < 4; ++k) smA[tid + 256 * k] = ldc(a.cbvec + tid + 256 * k);
    __syncthreads();
    float dq = 0.f, dk = 0.f, dv = 0.f;
    #pragma unroll
    for (int k = 0; k < 16; ++k){
      float x = smA[lane + 64 * k];
      dq = fmaf(wqr[k], x, dq); dk = fmaf(wkr[k], x, dk); dv = fmaf(wvr[k], x, dv);
    }
    aqcb = wsum(dq) + b_q; akcb = wsum(dk) + b_k; avcb = wsum(dv) + b_v;
    __syncthreads();
    #pragma unroll
    for (int k = 0; k < 4; ++k) smA[tid + 256 * k] = ldc(a.stylev + tid + 256 * k);
    __syncthreads();
    float sq = 0.f, sk = 0.f, sv = 0.f;
    #pragma unroll
    for (int k = 0; k < 16; ++k){
      float x = smA[lane + 64 * k];
      sq = fmaf(wqr[k], x, sq); sk = fmaf(wkr[k], x, sk); sv = fmaf(wvr[k], x, sv);
    }
    sq = wsum(sq); sk = wsum(sk); sv = wsum(sv);
    __syncthreads();
    float pq0 = 0.f, pk0 = 0.f, pv0 = 0.f;
    for (int p = 0; p < 30; ++p){
      #pragma unroll
      for (int k = 0; k < 4; ++k) smA[tid + 256 * k] = ldc(a.peT + (size_t)p * DIM + tid + 256 * k);
      __syncthreads();
      float tq = 0.f, tk = 0.f, tv = 0.f;
      #pragma unroll
      for (int k = 0; k < 16; ++k){
        float x = smA[lane + 64 * k];
        tq = fmaf(wqr[k], x, tq); tk = fmaf(wkr[k], x, tk); tv = fmaf(wvr[k], x, tv);
      }
      tq = wsum(tq); tk = wsum(tk); tv = wsum(tv);
      if (lane == 0){
        stc(a.wqpeT + (size_t)p * DIM + gw, tq);
        stc(a.wkpeT + (size_t)p * DIM + gw, tk);
        stc(a.wvpeT + (size_t)p * DIM + gw, tv);
      }
      if (p == 0){ pq0 = tq; pk0 = tk; pv0 = tv; }
      __syncthreads();
    }
    aq0 = sq + pq0 + b_q; ak0 = sk + pk0 + b_k; av0 = sv + pv0 + b_v;
  }
  ++bep; gsync(a.bar, bep, bid, tid);

  // ---- preload folded/main weight rows (128 floats/thread)
  float fq[16], fk[16], fv[16], wo[16], f1a[16], f1b[16], f2[32];
  {
    const float* pq = a.WqF + (size_t)gw * DIM;
    const float* pk = a.WkF + (size_t)gw * DIM;
    const float* pv = a.WvF + (size_t)gw * DIM;
    const float* po = a.sa_out_w + (size_t)gw * DIM;
    const float* p1a = a.ff1_w + (size_t)(2 * gw) * DIM;
    const float* p1b = a.ff1_w + (size_t)(2 * gw + 1) * DIM;
    const float* p2 = a.ff2_w + (size_t)gw * 2048;
    #pragma unroll
    for (int k = 0; k < 16; ++k){
      int d = lane + 64 * k;
      fq[k] = pq[d]; fk[k] = pk[d]; fv[k] = pv[d]; wo[k] = po[d];
      f1a[k] = p1a[d]; f1b[k] = p1b[d];
    }
    #pragma unroll
    for (int k = 0; k < 32; ++k) f2[k] = p2[lane + 64 * k];
  }
  const float b_o  = a.sa_out_b[gw];
  const float b_1a = a.ff1_b[2 * gw];
  const float b_1b = a.ff1_b[2 * gw + 1];
  const float b_2  = a.ff2_b[gw];
  const float b_vr = a.vr_b[gw];

  float c0 = 0.f, c1 = 0.f, c2 = 0.f, c3 = 0.f;
  const bool is_score = (bid < 16);
  const int sc_h  = bid >> 2;
  const int sc_jg = bid & 3;
  const float sc_slope = 1.0f / (float)(4 << (2 * sc_h));

  // ======== MS0: publish q/k/v for i=0; residual x0[gw] ========
  float xres;
  if (lane == 0){
    stc(a.q + gw, aq0);
    stc(a.kc + gw, ak0);
    stc(a.vcur + gw, av0);
  }
  xres = a.obj_w[(size_t)gw * 80] + ldc(a.peT + gw);
  ++bep; gsync(a.bar, bep, bid, tid);

  float vrr[16], cmr[16];
  for (int i = 0; i < SEQ; ++i){
    const unsigned ep = (unsigned)(i + 1);

    // ---- MS2: attention -> u  (c-update || scores -> replicated flags -> softmax)
    {
      #pragma unroll
      for (int k = 0; k < 4; ++k){
        smB[tid + 256 * k] = ldc(a.vcur + tid + 256 * k);
        smC[tid + 256 * k] = ldc(a.q + tid + 256 * k);
      }
      __syncthreads();
      float p0 = 0.f, p1 = 0.f, p2 = 0.f, p3 = 0.f;
      #pragma unroll
      for (int k = 0; k < 4; ++k){
        p0 = fmaf(wo[k],      smB[lane + 64 * k],        p0);
        p1 = fmaf(wo[k + 4],  smB[lane + 64 * (k + 4)],  p1);
        p2 = fmaf(wo[k + 8],  smB[lane + 64 * (k + 8)],  p2);
        p3 = fmaf(wo[k + 12], smB[lane + 64 * (k + 12)], p3);
      }
      p0 = wsum(p0); p1 = wsum(p1); p2 = wsum(p2); p3 = wsum(p3);
      if (lane == i){ c0 = p0; c1 = p1; c2 = p2; c3 = p3; }
      if (is_score){
        #pragma unroll
        for (int jj = 0; jj < 4; ++jj){
          int j = sc_jg * 16 + wave * 4 + jj;
          if (j <= i){
            const float* kr = a.kc + (size_t)j * DIM + sc_h * HDIM;
            float acc = 0.f;
            #pragma unroll
            for (int m = 0; m < 4; ++m)
              acc = fmaf(smC[sc_h * HDIM + m * 64 + lane], ldc(kr + m * 64 + lane), acc);
            acc = wsum(acc);
            if (lane == 0)
              stc(a.s + sc_h * 64 + j, acc * 0.0625f - sc_slope * (float)((i - j) / 30));
          }
        }
        asm volatile("s_waitcnt vmcnt(0)" ::: "memory");
        __syncthreads();
        if (tid == 0){
          #pragma unroll
          for (int r = 0; r < 8; ++r)
            sta(&a.flags[(bid * 8 + r) * SLOT_STRIDE], ep);
        }
      }
      if (tid < 16) spin_ge(&a.flags[(tid * 8 + (bid & 7)) * SLOT_STRIDE], ep);
      __syncthreads();
      {
        const int h = wave;
        float sv = (lane <= i) ? ldc(a.s + h * 64 + lane) : -3.0e38f;
        float mx = wmax(sv);
        float p = (lane <= i) ? __expf(sv - mx) : 0.f;
        float sum = wsum(p);
        scp[h * 64 + lane] = p / sum;
      }
      __syncthreads();
      float t = scp[lane] * c0 + scp[64 + lane] * c1 + scp[128 + lane] * c2 + scp[192 + lane] * c3;
      t = wsum(t);
      if (lane == 0) stc(a.u + gw, xres + t + b_o);
      __syncthreads();
    }
    ++bep; gsync(a.bar, bep, bid, tid);

    // ---- MS3: ln1 -> +cac -> ln2 ; ff1 -> hb
    float x2v;
    {
      float cr[4];
      #pragma unroll
      for (int k = 0; k < 4; ++k) cr[k] = ldc(a.cac + (size_t)i * DIM + tid + 256 * k);
      #pragma unroll
      for (int k = 0; k < 4; ++k) smA[tid + 256 * k] = ldc(a.u + tid + 256 * k);
      __syncthreads();
      float sa = 0.f, sb = 0.f;
      #pragma unroll
      for (int k = 0; k < 4; ++k){ float x = smA[tid + 256 * k]; sa += x; sb = fmaf(x, x, sb); }
      float2 r = breduce2(sa, sb, red);
      float mean = r.x * (1.f / 1024.f);
      float var  = r.y * (1.f / 1024.f) - mean * mean;
      float rs = 1.f / sqrtf(var + 1e-5f);
      float tv[4];
      float ta = 0.f, tb = 0.f;
      #pragma unroll
      for (int k = 0; k < 4; ++k){
        int d = tid + 256 * k;
        float x1 = (smA[d] - mean) * rs * a.ln1_g[d] + a.ln1_b[d];
        tv[k] = x1 + cr[k];
        ta += tv[k]; tb = fmaf(tv[k], tv[k], tb);
      }
      float2 r2v = breduce2(ta, tb, red);
      float mean2 = r2v.x * (1.f / 1024.f);
      float var2  = r2v.y * (1.f / 1024.f) - mean2 * mean2;
      float rs2 = 1.f / sqrtf(var2 + 1e-5f);
      #pragma unroll
      for (int k = 0; k < 4; ++k){
        int d = tid + 256 * k;
        smA[d] = (tv[k] - mean2) * rs2 * a.ln2_g[d] + a.ln2_b[d];
      }
      __syncthreads();
      x2v = smA[gw];
      float acc0 = 0.f, acc1 = 0.f;
      #pragma unroll
      for (int k = 0; k < 16; ++k){
        float x = smA[lane + 64 * k];
        acc0 = fmaf(f1a[k], x, acc0);
        acc1 = fmaf(f1b[k], x, acc1);
      }
      acc0 = wsum(acc0); acc1 = wsum(acc1);
      if (lane == 0){
        stc(a.hb + 2 * gw,     fmaxf(acc0 + b_1a, 0.f));
        stc(a.hb + 2 * gw + 1, fmaxf(acc1 + b_1b, 0.f));
      }
      __syncthreads();
    }
    ++bep; gsync(a.bar, bep, bid, tid);

    // ---- MS4: ff2 -> w ; prefetch vr_w/Cm rows
    {
      const float* pr = a.vr_w + (size_t)gw * DIM;
      const float* pc = a.Cm + (size_t)gw * DIM;
      #pragma unroll
      for (int k = 0; k < 16; ++k){ vrr[k] = pr[lane + 64 * k]; cmr[k] = pc[lane + 64 * k]; }
      #pragma unroll
      for (int k = 0; k < 8; ++k) smA[tid + 256 * k] = ldc(a.hb + tid + 256 * k);
      __syncthreads();
      float acc = 0.f;
      #pragma unroll
      for (int k = 0; k < 32; ++k) acc = fmaf(f2[k], smA[lane + 64 * k], acc);
      acc = wsum(acc);
      if (lane == 0) stc(a.w + gw, x2v + acc + b_2);
      __syncthreads();
    }
    ++bep; gsync(a.bar, bep, bid, tid);

    // ---- MS1': ln3 -> y ; out row i ; folded QKV + residual for i+1
    {
      #pragma unroll
      for (int k = 0; k < 4; ++k) smA[tid + 256 * k] = ldc(a.w + tid + 256 * k);
      __syncthreads();
      float sa = 0.f, sb = 0.f;
      #pragma unroll
      for (int k = 0; k < 4; ++k){ float x = smA[tid + 256 * k]; sa += x; sb = fmaf(x, x, sb); }
      float2 r = breduce2(sa, sb, red);
      float mean = r.x * (1.f / 1024.f);
      float var  = r.y * (1.f / 1024.f) - mean * mean;
      float rs = 1.f / sqrtf(var + 1e-5f);
      float ov[4];
      #pragma unroll
      for (int k = 0; k < 4; ++k){
        int d = tid + 256 * k;
        ov[k] = (smA[d] - mean) * rs * a.ln3_g[d] + a.ln3_b[d];
      }
      __syncthreads();
      #pragma unroll
      for (int k = 0; k < 4; ++k) smA[tid + 256 * k] = ov[k];
      __syncthreads();
      float ar = 0.f, ac = 0.f, aqn = 0.f, akn = 0.f, avn = 0.f;
      #pragma unroll
      for (int k = 0; k < 16; ++k){
        float x = smA[lane + 64 * k];
        ar  = fmaf(vrr[k], x, ar);
        ac  = fmaf(cmr[k], x, ac);
        aqn = fmaf(fq[k], x, aqn);
        akn = fmaf(fk[k], x, akn);
        avn = fmaf(fv[k], x, avn);
      }
      ar = wsum(ar); ac = wsum(ac);
      aqn = wsum(aqn); akn = wsum(akn); avn = wsum(avn);
      if (lane == 0) a.out[(size_t)i * DIM + gw] = ar + b_vr;
      if (i < SEQ - 1){
        int pn = (i + 1) % 30;
        if (lane == 0){
          float tq = ldc(a.wqpeT + (size_t)pn * DIM + gw);
          float tk = ldc(a.wkpeT + (size_t)pn * DIM + gw);
          float tv = ldc(a.wvpeT + (size_t)pn * DIM + gw);
          stc(a.q + gw, aqn + aqcb + tq);
          stc(a.kc + (size_t)(i + 1) * DIM + gw, akn + akcb + tk);
          stc(a.vcur + gw, avn + avcb + tv);
        }
        xres = ac + cbv + ldc(a.peT + (size_t)pn * DIM + gw);
        __syncthreads();
        ++bep; gsync(a.bar, bep, bid, tid);
      }
    }
  }
}

// ---------------- host launcher ----------------
extern "C" void kernel_launch(void* const* d_in, const int* in_sizes, int n_in,
                              void* d_out, int out_size, void* d_ws, size_t ws_size,
                              hipStream_t stream){
  const float* hs       = (const float*)d_in[0];
  const float* hid_w    = (const float*)d_in[1];
  const float* hid_b    = (const float*)d_in[2];
  const float* obj_w    = (const float*)d_in[3];
  const float* sa_in_w  = (const float*)d_in[4];
  const float* sa_in_b  = (const float*)d_in[5];
  const float* sa_out_w = (const float*)d_in[6];
  const float* sa_out_b = (const float*)d_in[7];
  const float* ca_in_w  = (const float*)d_in[8];
  const float* ca_in_b  = (const float*)d_in[9];
  const float* ca_out_w = (const float*)d_in[10];
  const float* ca_out_b = (const float*)d_in[11];
  const float* ln1_g    = (const float*)d_in[12];
  const float* ln1_b    = (const float*)d_in[13];
  const float* ln2_g    = (const float*)d_in[14];
  const float* ln2_b    = (const float*)d_in[15];
  const float* ln3_g    = (const float*)d_in[16];
  const float* ln3_b    = (const float*)d_in[17];
  const float* ff1_w    = (const float*)d_in[18];
  const float* ff1_b    = (const float*)d_in[19];
  const float* ff2_w    = (const float*)d_in[20];
  const float* ff2_b    = (const float*)d_in[21];
  const float* vr_w     = (const float*)d_in[22];
  const float* vr_b     = (const float*)d_in[23];
  const float* vm_w     = (const float*)d_in[24];
  const float* vm_b     = (const float*)d_in[25];

  float* ws = (float*)d_ws;
  float* mem    = ws;                 // 65536
  float* vtmp   = ws + 65536;         // 65536
  float* cac    = ws + 131072;        // 65536
  float* kc     = ws + 196608;        // 65536
  float* vcur   = ws + 262144;        // 1024
  float* q      = ws + 263168;        // 1024
  float* u      = ws + 264192;        // 1024
  float* hb     = ws + 265216;        // 2048
  float* wv     = ws + 267264;        // 1024
  float* sbuf   = ws + 268288;        // 1024
  float* peT    = ws + 269312;        // 30720
  float* stylev = ws + 300032;        // 1024
  float* cbvec  = ws + 301056;        // 1024
  float* wqpeT  = ws + 302080;        // 30720
  float* wkpeT  = ws + 332800;        // 30720
  float* wvpeT  = ws + 363520;        // 30720
  unsigned* bar   = (unsigned*)(ws + 394240);   // 512 lines x 128B = 64KB (slots+gflag+scfl)
  unsigned* flags = bar + 384 * SLOT_STRIDE;    // scfl base
  float* Cm     = ws + 425984;        // 1048576
  float* WqF    = ws + 1474560;       // 1048576 (Wq@Cm)
  float* WkF    = ws + 2523136;       // 1048576
  float* WvF    = ws + 3571712;       // 1048576  -> end 4620288 floats (18.5MB)

  // zero all sync lines (slots + gflag + scfl); re-poison safe
  hipMemsetAsync((void*)bar, 0, 512 * SLOT_STRIDE * 4, stream);

  // Cm = vm_w @ vr_w ; W{q,k,v}F = sa_in_w[z] @ Cm  (fast 64x64 tiled matmul)
  mm1024<<<dim3(16, 16, 1), 256, 0, stream>>>(vm_w, vr_w, Cm, 0, 0);
  mm1024<<<dim3(16, 16, 3), 256, 0, stream>>>(sa_in_w, Cm, WqF,
                                              (size_t)1024 * 1024, (size_t)1024 * 1024);

  CoopArgs A;
  A.hs = hs; A.hid_w = hid_w; A.hid_b = hid_b;
  A.sa_in_w = sa_in_w; A.sa_in_b = sa_in_b; A.sa_out_w = sa_out_w; A.sa_out_b = sa_out_b;
  A.ca_in_w = ca_in_w; A.ca_in_b = ca_in_b; A.ca_out_w = ca_out_w; A.ca_out_b = ca_out_b;
  A.ln1_g = ln1_g; A.ln1_b = ln1_b; A.ln2_g = ln2_g; A.ln2_b = ln2_b; A.ln3_g = ln3_g; A.ln3_b = ln3_b;
  A.ff1_w = ff1_w; A.ff1_b = ff1_b; A.ff2_w = ff2_w; A.ff2_b = ff2_b;
  A.vr_w = vr_w; A.vr_b = vr_b; A.vm_w = vm_w; A.vm_b = vm_b; A.obj_w = obj_w;
  A.Cm = Cm; A.WqF = WqF; A.WkF = WkF; A.WvF = WvF;
  A.mem = mem; A.vtmp = vtmp; A.cac = cac; A.kc = kc; A.vcur = vcur;
  A.q = q; A.u = u; A.hb = hb; A.w = wv; A.s = sbuf;
  A.peT = peT; A.stylev = stylev; A.cbvec = cbvec;
  A.wqpeT = wqpeT; A.wkpeT = wkpeT; A.wvpeT = wvpeT;
  A.out = (float*)d_out;
  A.bar = bar; A.flags = flags;

  void* params[1] = { &A };
  hipError_t e = hipLaunchCooperativeKernel((void*)decode_loop, dim3(NBLK), dim3(256), params, 0, stream);
  if (e != hipSuccess){
    decode_loop<<<dim3(NBLK), dim3(256), 0, stream>>>(A);
  }
}

// Round 15
// 2049.391 us; speedup vs baseline: 65.8351x; 1.1059x over previous
//
#include <hip/hip_runtime.h>
#include <math.h>

#define DIM  1024
#define SEQ  64
#define HDIM 256
#define NBLK 256
#define SLOT_STRIDE 32      // 32 u32 = 128 B
#define SENTU 0xFFC00ABCu   // NaN sentinel: computations never produce this pattern

// ---------------- wave / block reduction helpers ----------------
__device__ __forceinline__ float wsum(float v){
  v += __shfl_xor(v, 32, 64); v += __shfl_xor(v, 16, 64); v += __shfl_xor(v, 8, 64);
  v += __shfl_xor(v, 4, 64);  v += __shfl_xor(v, 2, 64);  v += __shfl_xor(v, 1, 64);
  return v;
}
__device__ __forceinline__ float wmax(float v){
  v = fmaxf(v, __shfl_xor(v, 32, 64)); v = fmaxf(v, __shfl_xor(v, 16, 64));
  v = fmaxf(v, __shfl_xor(v, 8, 64));  v = fmaxf(v, __shfl_xor(v, 4, 64));
  v = fmaxf(v, __shfl_xor(v, 2, 64));  v = fmaxf(v, __shfl_xor(v, 1, 64));
  return v;
}
__device__ __forceinline__ float2 breduce2(float va, float vb, float* red){
  int tid = threadIdx.x;
  va = wsum(va); vb = wsum(vb);
  if ((tid & 63) == 0){ red[(tid >> 6) * 2] = va; red[(tid >> 6) * 2 + 1] = vb; }
  __syncthreads();
  float ra = red[0] + red[2] + red[4] + red[6];
  float rb = red[1] + red[3] + red[5] + red[7];
  __syncthreads();
  return make_float2(ra, rb);
}

// ---------------- device-coherent primitives (R8-proven) ----------------
__device__ __forceinline__ float ldc(const float* p){
  return __hip_atomic_load(p, __ATOMIC_RELAXED, __HIP_MEMORY_SCOPE_AGENT);
}
__device__ __forceinline__ void stc(float* p, float v){
  __hip_atomic_store(p, v, __ATOMIC_RELAXED, __HIP_MEMORY_SCOPE_AGENT);
}
// sentinel poll: value arrives with its own validity (one-phase handoff)
__device__ __forceinline__ float plc(const float* p){
  float v = ldc(p);
  unsigned s = 0;
  while (__float_as_uint(v) == SENTU){ v = ldc(p); if (++s > 200000000u) break; }
  return v;
}
// poll 4 strided elements with all loads in flight per round (coalesced in-wave)
__device__ __forceinline__ void poll4s(const float* p, int stride, float* out){
  float v0 = ldc(p), v1 = ldc(p + stride), v2 = ldc(p + 2 * stride), v3 = ldc(p + 3 * stride);
  unsigned s = 0;
  while (__float_as_uint(v0) == SENTU || __float_as_uint(v1) == SENTU ||
         __float_as_uint(v2) == SENTU || __float_as_uint(v3) == SENTU){
    v0 = ldc(p); v1 = ldc(p + stride); v2 = ldc(p + 2 * stride); v3 = ldc(p + 3 * stride);
    if (++s > 200000000u) break;
  }
  out[0] = v0; out[1] = v1; out[2] = v2; out[3] = v3;
}

__device__ __forceinline__ void spin_ge(unsigned* p, unsigned ep){
  unsigned spins = 0;
  while (__hip_atomic_load(p, __ATOMIC_RELAXED, __HIP_MEMORY_SCOPE_AGENT) < ep){
    if (++spins > 100000000u) break;
  }
}
// flat barrier (R8-proven), prologue stages only
__device__ __forceinline__ void gsync(unsigned* slots, unsigned ep, int bid, int tid){
  asm volatile("s_waitcnt vmcnt(0)" ::: "memory");
  __syncthreads();
  if (tid == 0)
    __hip_atomic_store(&slots[bid * SLOT_STRIDE], ep, __ATOMIC_RELAXED, __HIP_MEMORY_SCOPE_AGENT);
  spin_ge(&slots[tid * SLOT_STRIDE], ep);
  __syncthreads();
  asm volatile("" ::: "memory");
}

// ---------------- prologue matmul: 64x64 tile, 4x4 per thread ----------------
__global__ void mm1024(const float* __restrict__ A0, const float* __restrict__ B,
                       float* __restrict__ C0, size_t Astride, size_t Cstride){
  const float* A = A0 + (size_t)blockIdx.z * Astride;
  float* C = C0 + (size_t)blockIdx.z * Cstride;
  __shared__ float As[16][65];
  __shared__ float Bs[16][65];
  int ta = blockIdx.y * 64, tb = blockIdx.x * 64;
  int tx = threadIdx.x & 15, ty = threadIdx.x >> 4;
  float acc[4][4] = {};
  for (int k0 = 0; k0 < 1024; k0 += 16){
    #pragma unroll
    for (int j = 0; j < 4; ++j)
      As[tx][ty * 4 + j] = A[(size_t)(ta + ty * 4 + j) * 1024 + k0 + tx];
    {
      const float4 bv = *(const float4*)&B[(size_t)(k0 + ty) * 1024 + tb + tx * 4];
      Bs[ty][tx * 4]     = bv.x; Bs[ty][tx * 4 + 1] = bv.y;
      Bs[ty][tx * 4 + 2] = bv.z; Bs[ty][tx * 4 + 3] = bv.w;
    }
    __syncthreads();
    #pragma unroll
    for (int kk = 0; kk < 16; ++kk){
      float av[4], bv[4];
      #pragma unroll
      for (int m = 0; m < 4; ++m) av[m] = As[kk][ty * 4 + m];
      #pragma unroll
      for (int n = 0; n < 4; ++n) bv[n] = Bs[kk][tx * 4 + n];
      #pragma unroll
      for (int m = 0; m < 4; ++m)
        #pragma unroll
        for (int n = 0; n < 4; ++n) acc[m][n] = fmaf(av[m], bv[n], acc[m][n]);
    }
    __syncthreads();
  }
  #pragma unroll
  for (int m = 0; m < 4; ++m){
    float4 ov = { acc[m][0], acc[m][1], acc[m][2], acc[m][3] };
    *(float4*)&C[(size_t)(ta + ty * 4 + m) * 1024 + tb + tx * 4] = ov;
  }
}

// sentinel-fill the write-once dataflow arrays (runs every launch; re-poison safe)
__global__ void sentinit(unsigned* p, size_t n){
  size_t idx = (size_t)blockIdx.x * 256 + threadIdx.x;
  for (size_t k = idx; k < n; k += (size_t)gridDim.x * 256) p[k] = SENTU;
}

// ---------------- the persistent autoregressive decode ----------------
struct CoopArgs {
  const float *hs, *hid_w, *hid_b;
  const float *sa_in_w, *sa_in_b, *sa_out_w, *sa_out_b;
  const float *ca_in_w, *ca_in_b, *ca_out_w, *ca_out_b;
  const float *ln1_g, *ln1_b, *ln2_g, *ln2_b, *ln3_g, *ln3_b;
  const float *ff1_w, *ff1_b, *ff2_w, *ff2_b;
  const float *vr_w, *vr_b, *vm_w, *vm_b, *obj_w;
  const float *Cm, *WqF, *WkF, *WvF;
  float *mem, *vtmp, *cac;
  float *kc, *qv, *vcB, *uB, *hbB, *wB, *sB;   // write-once dataflow arrays
  float *peT, *stylev, *cbvec, *wqpeT, *wkpeT, *wvpeT;
  float *out;
  unsigned *bar;
};

__global__ void __launch_bounds__(256, 2) decode_loop(CoopArgs a){
  const int tid = threadIdx.x, bid = blockIdx.x;
  const int wave = tid >> 6, lane = tid & 63;
  const int gw = bid * 4 + wave;            // global wave id / row, 0..1023
  __shared__ float smA[2048];
  __shared__ float smB[1024];
  __shared__ float scp[256];
  __shared__ float red[8];
  unsigned bep = 0;
  const float NLOG = -9.210340371976184f / 1024.0f;   // -ln(10000)/D

  // ======== P1: mem rows; pe table; style vector ========
  {
    float pw[16];
    const float* pr = a.hid_w + (size_t)gw * DIM;
    #pragma unroll
    for (int k = 0; k < 16; ++k) pw[k] = pr[lane + 64 * k];
    float bias = a.hid_b[gw];
    for (int t = 0; t < 64; ++t){
      const float* xr = a.hs + (size_t)t * DIM;
      float acc = 0.f;
      #pragma unroll
      for (int k = 0; k < 16; ++k) acc = fmaf(pw[k], xr[lane + 64 * k], acc);
      acc = wsum(acc);
      if (lane == 0) stc(a.mem + (size_t)t * DIM + gw, acc + bias);
    }
    if (bid < 30){
      int p = bid;
      for (int d = tid; d < DIM; d += 256){
        float dv = __expf((float)(2 * (d >> 1)) * NLOG);
        float arg = (float)p * dv;
        stc(a.peT + (size_t)p * DIM + d, (d & 1) ? cosf(arg) : sinf(arg));
      }
    } else if (bid == 30){
      for (int d = tid; d < DIM; d += 256) stc(a.stylev + d, a.obj_w[(size_t)d * 80]);
    }
  }
  ++bep; gsync(a.bar, bep, bid, tid);

  // ======== P2: vtmp rows; cb vector ========
  float cbv;
  {
    const float* pv = a.vm_w + (size_t)gw * DIM;
    float acc = 0.f;
    #pragma unroll
    for (int k = 0; k < 16; ++k) acc = fmaf(pv[lane + 64 * k], a.vr_b[lane + 64 * k], acc);
    acc = wsum(acc);
    cbv = acc + a.vm_b[gw] + ldc(a.stylev + gw);
    if (lane == 0) stc(a.cbvec + gw, cbv);
  }
  {
    float pw[16];
    const float* pr = a.ca_in_w + (size_t)(2 * DIM + gw) * DIM;
    #pragma unroll
    for (int k = 0; k < 16; ++k) pw[k] = pr[lane + 64 * k];
    float bias = a.ca_in_b[2 * DIM + gw];
    for (int t = 0; t < 64; ++t){
      const float* xr = a.mem + (size_t)t * DIM;
      #pragma unroll
      for (int k = 0; k < 4; ++k) smA[tid + 256 * k] = ldc(xr + tid + 256 * k);
      __syncthreads();
      float acc = 0.f;
      #pragma unroll
      for (int k = 0; k < 16; ++k) acc = fmaf(pw[k], smA[lane + 64 * k], acc);
      acc = wsum(acc);
      if (lane == 0) stc(a.vtmp + (size_t)t * DIM + gw, acc + bias);
      __syncthreads();
    }
  }
  ++bep; gsync(a.bar, bep, bid, tid);

  // ======== P3: cac rows ========
  {
    float pw[16];
    const float* pr = a.ca_out_w + (size_t)gw * DIM;
    #pragma unroll
    for (int k = 0; k < 16; ++k) pw[k] = pr[lane + 64 * k];
    float bias = a.ca_out_b[gw];
    for (int t = 0; t < 64; ++t){
      const float* xr = a.vtmp + (size_t)t * DIM;
      #pragma unroll
      for (int k = 0; k < 4; ++k) smA[tid + 256 * k] = ldc(xr + tid + 256 * k);
      __syncthreads();
      float acc = 0.f;
      #pragma unroll
      for (int k = 0; k < 16; ++k) acc = fmaf(pw[k], smA[lane + 64 * k], acc);
      acc = wsum(acc);
      if (lane == 0) stc(a.cac + (size_t)t * DIM + gw, acc + bias);
      __syncthreads();
    }
  }
  ++bep; gsync(a.bar, bep, bid, tid);

  // ======== PB: per-row QKV constants (W.cb, W.style, W.pe[p]); publish i=0 q/k/v ========
  float aqcb, akcb, avcb;
  {
    float wqr[16], wkr[16], wvr[16];
    const float* pq = a.sa_in_w + (size_t)gw * DIM;
    const float* pk = a.sa_in_w + (size_t)(DIM + gw) * DIM;
    const float* pv = a.sa_in_w + (size_t)(2 * DIM + gw) * DIM;
    #pragma unroll
    for (int k = 0; k < 16; ++k){
      int d = lane + 64 * k;
      wqr[k] = pq[d]; wkr[k] = pk[d]; wvr[k] = pv[d];
    }
    const float b_q = a.sa_in_b[gw];
    const float b_k = a.sa_in_b[DIM + gw];
    const float b_v = a.sa_in_b[2 * DIM + gw];
    float dq = 0.f, dk = 0.f, dv = 0.f, sq = 0.f, sk = 0.f, sv = 0.f;
    #pragma unroll
    for (int k = 0; k < 16; ++k){
      float xc = ldc(a.cbvec + lane + 64 * k);
      float xs = ldc(a.stylev + lane + 64 * k);
      dq = fmaf(wqr[k], xc, dq); dk = fmaf(wkr[k], xc, dk); dv = fmaf(wvr[k], xc, dv);
      sq = fmaf(wqr[k], xs, sq); sk = fmaf(wkr[k], xs, sk); sv = fmaf(wvr[k], xs, sv);
    }
    aqcb = wsum(dq) + b_q; akcb = wsum(dk) + b_k; avcb = wsum(dv) + b_v;
    sq = wsum(sq); sk = wsum(sk); sv = wsum(sv);
    float pq0 = 0.f, pk0 = 0.f, pv0 = 0.f;
    for (int p = 0; p < 30; ++p){
      const float* pp = a.peT + (size_t)p * DIM;
      float tq = 0.f, tk = 0.f, tv = 0.f;
      #pragma unroll
      for (int k = 0; k < 16; ++k){
        float x = ldc(pp + lane + 64 * k);
        tq = fmaf(wqr[k], x, tq); tk = fmaf(wkr[k], x, tk); tv = fmaf(wvr[k], x, tv);
      }
      tq = wsum(tq); tk = wsum(tk); tv = wsum(tv);
      if (lane == 0){
        stc(a.wqpeT + (size_t)p * DIM + gw, tq);
        stc(a.wkpeT + (size_t)p * DIM + gw, tk);
        stc(a.wvpeT + (size_t)p * DIM + gw, tv);
      }
      if (p == 0){ pq0 = tq; pk0 = tk; pv0 = tv; }
    }
    // publish i=0 q/k/v via dataflow stores (consumers sentinel-poll)
    if (lane == 0){
      stc(a.qv + gw, sq + pq0 + b_q);
      stc(a.kc + gw, sk + pk0 + b_k);
      stc(a.vcB + gw, sv + pv0 + b_v);
    }
  }
  ++bep; gsync(a.bar, bep, bid, tid);   // wqpeT tables must be globally visible

  // ---- preload folded/main weight rows (128 floats/thread)
  float fq[16], fk[16], fv[16], wo[16], f1a[16], f1b[16], f2[32];
  {
    const float* pq = a.WqF + (size_t)gw * DIM;
    const float* pk = a.WkF + (size_t)gw * DIM;
    const float* pv = a.WvF + (size_t)gw * DIM;
    const float* po = a.sa_out_w + (size_t)gw * DIM;
    const float* p1a = a.ff1_w + (size_t)(2 * gw) * DIM;
    const float* p1b = a.ff1_w + (size_t)(2 * gw + 1) * DIM;
    const float* p2 = a.ff2_w + (size_t)gw * 2048;
    #pragma unroll
    for (int k = 0; k < 16; ++k){
      int d = lane + 64 * k;
      fq[k] = pq[d]; fk[k] = pk[d]; fv[k] = pv[d]; wo[k] = po[d];
      f1a[k] = p1a[d]; f1b[k] = p1b[d];
    }
    #pragma unroll
    for (int k = 0; k < 32; ++k) f2[k] = p2[lane + 64 * k];
  }
  const float b_o  = a.sa_out_b[gw];
  const float b_1a = a.ff1_b[2 * gw];
  const float b_1b = a.ff1_b[2 * gw + 1];
  const float b_2  = a.ff2_b[gw];
  const float b_vr = a.vr_b[gw];

  float c0 = 0.f, c1 = 0.f, c2 = 0.f, c3 = 0.f;
  const bool is_score = (bid < 16);
  const int sc_h  = bid >> 2;
  const int sc_jg = bid & 3;
  const float sc_slope = 1.0f / (float)(4 << (2 * sc_h));

  float xres = a.obj_w[(size_t)gw * 80] + ldc(a.peT + gw);
  float vrr[16], cmr[16];

  for (int i = 0; i < SEQ; ++i){
    // ---- MS2: attention -> u  (dataflow: poll V row, scores, softmax)
    {
      float vv[4];
      poll4s(a.vcB + (size_t)i * DIM + tid, 256, vv);
      smB[tid] = vv[0]; smB[tid + 256] = vv[1]; smB[tid + 512] = vv[2]; smB[tid + 768] = vv[3];
      __syncthreads();
      float p0 = 0.f, p1 = 0.f, p2 = 0.f, p3 = 0.f;
      #pragma unroll
      for (int k = 0; k < 4; ++k){
        p0 = fmaf(wo[k],      smB[lane + 64 * k],        p0);
        p1 = fmaf(wo[k + 4],  smB[lane + 64 * (k + 4)],  p1);
        p2 = fmaf(wo[k + 8],  smB[lane + 64 * (k + 8)],  p2);
        p3 = fmaf(wo[k + 12], smB[lane + 64 * (k + 12)], p3);
      }
      p0 = wsum(p0); p1 = wsum(p1); p2 = wsum(p2); p3 = wsum(p3);
      if (lane == i){ c0 = p0; c1 = p1; c2 = p2; c3 = p3; }
      if (is_score){
        float q4[4];
        poll4s(a.qv + (size_t)i * DIM + sc_h * HDIM + lane, 64, q4);
        #pragma unroll
        for (int jj = 0; jj < 4; ++jj){
          int j = sc_jg * 16 + wave * 4 + jj;
          if (j <= i){
            const float* kr = a.kc + (size_t)j * DIM + sc_h * HDIM + lane;
            float acc = 0.f;
            #pragma unroll
            for (int m = 0; m < 4; ++m) acc = fmaf(q4[m], plc(kr + m * 64), acc);
            acc = wsum(acc);
            if (lane == 0)
              stc(a.sB + (size_t)i * 256 + sc_h * 64 + j,
                  acc * 0.0625f - sc_slope * (float)((i - j) / 30));
          }
        }
      }
      float sv = (lane <= i) ? plc(a.sB + (size_t)i * 256 + wave * 64 + lane) : -3.0e38f;
      float mx = wmax(sv);
      float p = (lane <= i) ? __expf(sv - mx) : 0.f;
      float sum = wsum(p);
      scp[wave * 64 + lane] = p / sum;
      __syncthreads();
      float t = scp[lane] * c0 + scp[64 + lane] * c1 + scp[128 + lane] * c2 + scp[192 + lane] * c3;
      t = wsum(t);
      if (lane == 0) stc(a.uB + (size_t)i * DIM + gw, xres + t + b_o);
      __syncthreads();
    }

    // ---- MS3: ln1 -> +cac -> ln2 ; ff1 -> hb
    float x2v;
    {
      float cr[4];
      #pragma unroll
      for (int k = 0; k < 4; ++k) cr[k] = ldc(a.cac + (size_t)i * DIM + tid + 256 * k);
      float uv[4];
      poll4s(a.uB + (size_t)i * DIM + tid, 256, uv);
      smA[tid] = uv[0]; smA[tid + 256] = uv[1]; smA[tid + 512] = uv[2]; smA[tid + 768] = uv[3];
      __syncthreads();
      float sa = 0.f, sb = 0.f;
      #pragma unroll
      for (int k = 0; k < 4; ++k){ float x = smA[tid + 256 * k]; sa += x; sb = fmaf(x, x, sb); }
      float2 r = breduce2(sa, sb, red);
      float mean = r.x * (1.f / 1024.f);
      float var  = r.y * (1.f / 1024.f) - mean * mean;
      float rs = 1.f / sqrtf(var + 1e-5f);
      float tv[4];
      float ta = 0.f, tb = 0.f;
      #pragma unroll
      for (int k = 0; k < 4; ++k){
        int d = tid + 256 * k;
        float x1 = (smA[d] - mean) * rs * a.ln1_g[d] + a.ln1_b[d];
        tv[k] = x1 + cr[k];
        ta += tv[k]; tb = fmaf(tv[k], tv[k], tb);
      }
      float2 r2v = breduce2(ta, tb, red);
      float mean2 = r2v.x * (1.f / 1024.f);
      float var2  = r2v.y * (1.f / 1024.f) - mean2 * mean2;
      float rs2 = 1.f / sqrtf(var2 + 1e-5f);
      #pragma unroll
      for (int k = 0; k < 4; ++k){
        int d = tid + 256 * k;
        smA[d] = (tv[k] - mean2) * rs2 * a.ln2_g[d] + a.ln2_b[d];
      }
      __syncthreads();
      x2v = smA[gw];
      float acc0 = 0.f, acc1 = 0.f;
      #pragma unroll
      for (int k = 0; k < 16; ++k){
        float x = smA[lane + 64 * k];
        acc0 = fmaf(f1a[k], x, acc0);
        acc1 = fmaf(f1b[k], x, acc1);
      }
      acc0 = wsum(acc0); acc1 = wsum(acc1);
      if (lane == 0){
        stc(a.hbB + (size_t)i * 2048 + 2 * gw,     fmaxf(acc0 + b_1a, 0.f));
        stc(a.hbB + (size_t)i * 2048 + 2 * gw + 1, fmaxf(acc1 + b_1b, 0.f));
      }
      __syncthreads();
    }

    // ---- MS4: ff2 -> w ; prefetch vr_w/Cm rows
    {
      const float* pr = a.vr_w + (size_t)gw * DIM;
      const float* pc = a.Cm + (size_t)gw * DIM;
      #pragma unroll
      for (int k = 0; k < 16; ++k){ vrr[k] = pr[lane + 64 * k]; cmr[k] = pc[lane + 64 * k]; }
      float h0[4], h1[4];
      poll4s(a.hbB + (size_t)i * 2048 + tid, 256, h0);
      poll4s(a.hbB + (size_t)i * 2048 + 1024 + tid, 256, h1);
      #pragma unroll
      for (int k = 0; k < 4; ++k){ smA[tid + 256 * k] = h0[k]; smA[tid + 1024 + 256 * k] = h1[k]; }
      __syncthreads();
      float acc = 0.f;
      #pragma unroll
      for (int k = 0; k < 32; ++k) acc = fmaf(f2[k], smA[lane + 64 * k], acc);
      acc = wsum(acc);
      if (lane == 0) stc(a.wB + (size_t)i * DIM + gw, x2v + acc + b_2);
      __syncthreads();
    }

    // ---- MS1': ln3 -> y ; out row i ; folded QKV + residual for i+1
    {
      float wv4[4];
      poll4s(a.wB + (size_t)i * DIM + tid, 256, wv4);
      smA[tid] = wv4[0]; smA[tid + 256] = wv4[1]; smA[tid + 512] = wv4[2]; smA[tid + 768] = wv4[3];
      __syncthreads();
      float sa = 0.f, sb = 0.f;
      #pragma unroll
      for (int k = 0; k < 4; ++k){ float x = smA[tid + 256 * k]; sa += x; sb = fmaf(x, x, sb); }
      float2 r = breduce2(sa, sb, red);
      float mean = r.x * (1.f / 1024.f);
      float var  = r.y * (1.f / 1024.f) - mean * mean;
      float rs = 1.f / sqrtf(var + 1e-5f);
      float ov[4];
      #pragma unroll
      for (int k = 0; k < 4; ++k){
        int d = tid + 256 * k;
        ov[k] = (smA[d] - mean) * rs * a.ln3_g[d] + a.ln3_b[d];
      }
      __syncthreads();
      #pragma unroll
      for (int k = 0; k < 4; ++k) smA[tid + 256 * k] = ov[k];
      __syncthreads();
      float ar = 0.f, ac = 0.f, aqn = 0.f, akn = 0.f, avn = 0.f;
      #pragma unroll
      for (int k = 0; k < 16; ++k){
        float x = smA[lane + 64 * k];
        ar  = fmaf(vrr[k], x, ar);
        ac  = fmaf(cmr[k], x, ac);
        aqn = fmaf(fq[k], x, aqn);
        akn = fmaf(fk[k], x, akn);
        avn = fmaf(fv[k], x, avn);
      }
      ar = wsum(ar); ac = wsum(ac);
      aqn = wsum(aqn); akn = wsum(akn); avn = wsum(avn);
      if (lane == 0) a.out[(size_t)i * DIM + gw] = ar + b_vr;
      if (i < SEQ - 1){
        int pn = (i + 1) % 30;
        if (lane == 0){
          float tq = ldc(a.wqpeT + (size_t)pn * DIM + gw);
          float tk = ldc(a.wkpeT + (size_t)pn * DIM + gw);
          float tv = ldc(a.wvpeT + (size_t)pn * DIM + gw);
          stc(a.qv + (size_t)(i + 1) * DIM + gw, aqn + aqcb + tq);
          stc(a.kc + (size_t)(i + 1) * DIM + gw, akn + akcb + tk);
          stc(a.vcB + (size_t)(i + 1) * DIM + gw, avn + avcb + tv);
        }
        xres = ac + cbv + ldc(a.peT + (size_t)pn * DIM + gw);
      }
      __syncthreads();
    }
  }
}

// ---------------- host launcher ----------------
extern "C" void kernel_launch(void* const* d_in, const int* in_sizes, int n_in,
                              void* d_out, int out_size, void* d_ws, size_t ws_size,
                              hipStream_t stream){
  const float* hs       = (const float*)d_in[0];
  const float* hid_w    = (const float*)d_in[1];
  const float* hid_b    = (const float*)d_in[2];
  const float* obj_w    = (const float*)d_in[3];
  const float* sa_in_w  = (const float*)d_in[4];
  const float* sa_in_b  = (const float*)d_in[5];
  const float* sa_out_w = (const float*)d_in[6];
  const float* sa_out_b = (const float*)d_in[7];
  const float* ca_in_w  = (const float*)d_in[8];
  const float* ca_in_b  = (const float*)d_in[9];
  const float* ca_out_w = (const float*)d_in[10];
  const float* ca_out_b = (const float*)d_in[11];
  const float* ln1_g    = (const float*)d_in[12];
  const float* ln1_b    = (const float*)d_in[13];
  const float* ln2_g    = (const float*)d_in[14];
  const float* ln2_b    = (const float*)d_in[15];
  const float* ln3_g    = (const float*)d_in[16];
  const float* ln3_b    = (const float*)d_in[17];
  const float* ff1_w    = (const float*)d_in[18];
  const float* ff1_b    = (const float*)d_in[19];
  const float* ff2_w    = (const float*)d_in[20];
  const float* ff2_b    = (const float*)d_in[21];
  const float* vr_w     = (const float*)d_in[22];
  const float* vr_b     = (const float*)d_in[23];
  const float* vm_w     = (const float*)d_in[24];
  const float* vm_b     = (const float*)d_in[25];

  float* ws = (float*)d_ws;
  float* mem    = ws;                 // 65536
  float* vtmp   = ws + 65536;         // 65536
  float* cac    = ws + 131072;        // 65536
  // ---- write-once dataflow region (sentinel-initialized each launch) ----
  float* kc     = ws + 196608;        // 65536  [64][1024]
  float* qv     = ws + 262144;        // 65536
  float* vcB    = ws + 327680;        // 65536
  float* uB     = ws + 393216;        // 65536
  float* hbB    = ws + 458752;        // 131072 [64][2048]
  float* wB     = ws + 589824;        // 65536
  float* sB     = ws + 655360;        // 16384  [64][256]
  // ---- constants / tables ----
  float* peT    = ws + 671744;        // 30720
  float* stylev = ws + 702464;        // 1024
  float* cbvec  = ws + 703488;        // 1024
  float* wqpeT  = ws + 704512;        // 30720
  float* wkpeT  = ws + 735232;        // 30720
  float* wvpeT  = ws + 765952;        // 30720
  unsigned* bar = (unsigned*)(ws + 796672);   // 256 lines x 128B = 32KB
  float* Cm     = ws + 804864;        // 1048576
  float* WqF    = ws + 1853440;       // 1048576
  float* WkF    = ws + 2902016;       // 1048576
  float* WvF    = ws + 3950592;       // 1048576 -> end 4999168 floats (~20MB)

  hipMemsetAsync((void*)bar, 0, 256 * SLOT_STRIDE * 4, stream);
  sentinit<<<512, 256, 0, stream>>>((unsigned*)kc, 475136);   // kc..sB

  mm1024<<<dim3(16, 16, 1), 256, 0, stream>>>(vm_w, vr_w, Cm, 0, 0);
  mm1024<<<dim3(16, 16, 3), 256, 0, stream>>>(sa_in_w, Cm, WqF,
                                              (size_t)1024 * 1024, (size_t)1024 * 1024);

  CoopArgs A;
  A.hs = hs; A.hid_w = hid_w; A.hid_b = hid_b;
  A.sa_in_w = sa_in_w; A.sa_in_b = sa_in_b; A.sa_out_w = sa_out_w; A.sa_out_b = sa_out_b;
  A.ca_in_w = ca_in_w; A.ca_in_b = ca_in_b; A.ca_out_w = ca_out_w; A.ca_out_b = ca_out_b;
  A.ln1_g = ln1_g; A.ln1_b = ln1_b; A.ln2_g = ln2_g; A.ln2_b = ln2_b; A.ln3_g = ln3_g; A.ln3_b = ln3_b;
  A.ff1_w = ff1_w; A.ff1_b = ff1_b; A.ff2_w = ff2_w; A.ff2_b = ff2_b;
  A.vr_w = vr_w; A.vr_b = vr_b; A.vm_w = vm_w; A.vm_b = vm_b; A.obj_w = obj_w;
  A.Cm = Cm; A.WqF = WqF; A.WkF = WkF; A.WvF = WvF;
  A.mem = mem; A.vtmp = vtmp; A.cac = cac;
  A.kc = kc; A.qv = qv; A.vcB = vcB; A.uB = uB; A.hbB = hbB; A.wB = wB; A.sB = sB;
  A.peT = peT; A.stylev = stylev; A.cbvec = cbvec;
  A.wqpeT = wqpeT; A.wkpeT = wkpeT; A.wvpeT = wvpeT;
  A.out = (float*)d_out;
  A.bar = bar;

  void* params[1] = { &A };
  hipError_t e = hipLaunchCooperativeKernel((void*)decode_loop, dim3(NBLK), dim3(256), params, 0, stream);
  if (e != hipSuccess){
    decode_loop<<<dim3(NBLK), dim3(256), 0, stream>>>(A);
  }
}